// Round 10
// baseline (489.319 us; speedup 1.0000x reference)
//
#include <hip/hip_runtime.h>
#include <hip/hip_bf16.h>

// ---------------------------------------------------------------------------
// DGL GAT (2-layer, heads=4, out=32) + WeightedSumAndMax readout.
// Round 9: paired-edge lane layout in agg kernels — lane = parity*32 + col
//          group(4 cols, uint2 gather). Halves per-edge VALU + load count at
//          constant bytes; straight-line 4-pair body (r5's regression was
//          predication, not width). xor-32 parity combine.
// ---------------------------------------------------------------------------

#define HEADS 4
#define OUTF 32
#define HF 128            // HEADS*OUTF
#define IN_FEATS 74
#define PRED_DIM 128
#define NEG_SLOPE 0.2f
#define NEG_INF_ENC 0x007fffffu   // enc_f(-inf)

typedef __hip_bfloat16 bf16;
typedef __hip_bfloat162 bf16x2;

__device__ __forceinline__ unsigned enc_f(float f) {
  unsigned u = __float_as_uint(f);
  return (u & 0x80000000u) ? ~u : (u | 0x80000000u);
}
__device__ __forceinline__ float dec_f(unsigned k) {
  return (k & 0x80000000u) ? __uint_as_float(k & 0x7fffffffu)
                           : __uint_as_float(~k);
}
__device__ __forceinline__ unsigned pack_bf16(float a, float b) {
  bf16x2 h = __float22bfloat162_rn(make_float2(a, b));
  return *(unsigned*)&h;
}
__device__ __forceinline__ float2 unpack_bf16(unsigned u) {
  bf16x2 h = *(bf16x2*)&u;
  return __bfloat1622float2(h);
}
// leaky_relu(v, 0.2) == max(v, 0.2*v)
__device__ __forceinline__ float lrelu(float v) {
  return fmaxf(v, NEG_SLOPE * v);
}
__device__ __forceinline__ float ld_f(const float* p) { return *p; }
__device__ __forceinline__ float ld_f(const bf16* p) {
  return __bfloat162float(*p);
}

// ========================= node GEMM =============================
// out[n][j] = dot(X[n,:K], W[:K,j]), bf16 output. 64 nodes x 128 cols/block,
// 8x4 per thread. SCORES: fused el/er epilogue.
template <int K, typename XT, bool SCORES>
__global__ __launch_bounds__(256) void gemm_tiled(
    const XT* __restrict__ X, const float* __restrict__ W,
    const float* __restrict__ attn_l, const float* __restrict__ attn_r,
    bf16* __restrict__ out, float* __restrict__ el, float* __restrict__ er,
    int N) {
  constexpr int BK = 32;
  constexpr int APAD = 68;
  __shared__ float as[BK * APAD];
  __shared__ float bs[BK * HF];
  const int tid = threadIdx.x;
  const int tx = tid & 31;
  const int ty = tid >> 5;
  const int j4 = tx * 4;
  const int nb = ty * 8;
  const int n0 = blockIdx.x * 64;

  float acc[8][4] = {};
  for (int k0 = 0; k0 < K; k0 += BK) {
#pragma unroll
    for (int i = 0; i < 8; ++i) {
      int idx = i * 256 + tid;
      int kk = idx & 31, nl = idx >> 5;
      int n = n0 + nl, k = k0 + kk;
      float v = 0.f;
      if (n < N && k < K) v = ld_f(&X[(size_t)n * K + k]);
      as[kk * APAD + nl] = v;
    }
#pragma unroll
    for (int i = 0; i < 16; ++i) {
      int idx = i * 256 + tid;
      int kk = idx >> 7, c = idx & 127;
      int k = k0 + kk;
      bs[idx] = (k < K) ? W[(size_t)k * HF + c] : 0.f;
    }
    __syncthreads();
#pragma unroll 8
    for (int kk = 0; kk < BK; ++kk) {
      float4 wv = *(const float4*)&bs[kk * HF + j4];
      float4 a0 = *(const float4*)&as[kk * APAD + nb];
      float4 a1 = *(const float4*)&as[kk * APAD + nb + 4];
      float av[8] = {a0.x, a0.y, a0.z, a0.w, a1.x, a1.y, a1.z, a1.w};
#pragma unroll
      for (int i = 0; i < 8; ++i) {
        acc[i][0] = fmaf(av[i], wv.x, acc[i][0]);
        acc[i][1] = fmaf(av[i], wv.y, acc[i][1]);
        acc[i][2] = fmaf(av[i], wv.z, acc[i][2]);
        acc[i][3] = fmaf(av[i], wv.w, acc[i][3]);
      }
    }
    __syncthreads();
  }
#pragma unroll
  for (int i = 0; i < 8; ++i) {
    int n = n0 + nb + i;
    if (n < N)
      *(uint2*)&out[(size_t)n * HF + j4] =
          make_uint2(pack_bf16(acc[i][0], acc[i][1]),
                     pack_bf16(acc[i][2], acc[i][3]));
  }
  if (SCORES) {
    float al0 = attn_l[j4], al1 = attn_l[j4 + 1];
    float al2 = attn_l[j4 + 2], al3 = attn_l[j4 + 3];
    float ar0 = attn_r[j4], ar1 = attn_r[j4 + 1];
    float ar2 = attn_r[j4 + 2], ar3 = attn_r[j4 + 3];
    const int h = tx >> 3;
#pragma unroll
    for (int i = 0; i < 8; ++i) {
      float pl = acc[i][0] * al0 + acc[i][1] * al1 +
                 acc[i][2] * al2 + acc[i][3] * al3;
      float pr = acc[i][0] * ar0 + acc[i][1] * ar1 +
                 acc[i][2] * ar2 + acc[i][3] * ar3;
      pl += __shfl_xor(pl, 1); pr += __shfl_xor(pr, 1);
      pl += __shfl_xor(pl, 2); pr += __shfl_xor(pr, 2);
      pl += __shfl_xor(pl, 4); pr += __shfl_xor(pr, 4);
      int n = n0 + nb + i;
      if ((tx & 7) == 0 && n < N) {
        el[n * HEADS + h] = pl;
        er[n * HEADS + h] = pr;
      }
    }
  }
}

// ============================ CSR build ====================================
__global__ __launch_bounds__(256) void hist_kernel(
    const int* __restrict__ dst, int* __restrict__ deg, int E) {
  int e = blockIdx.x * 256 + threadIdx.x;
  if (e < E) atomicAdd(&deg[dst[e]], 1);
}

__global__ __launch_bounds__(256) void scan1_kernel(
    const int* __restrict__ deg, int* __restrict__ row_ptr,
    int* __restrict__ bsum, int N) {
  const int base = blockIdx.x * 2048;
  const int tbase = base + threadIdx.x * 8;
  int vals[8];
  int tsum = 0;
#pragma unroll
  for (int i = 0; i < 8; ++i) {
    int idx = tbase + i;
    vals[i] = (idx < N) ? deg[idx] : 0;
    tsum += vals[i];
  }
  const int lane = threadIdx.x & 63, wv = threadIdx.x >> 6;
  int incl = tsum;
#pragma unroll
  for (int off = 1; off < 64; off <<= 1) {
    int nv = __shfl_up(incl, off);
    if (lane >= off) incl += nv;
  }
  __shared__ int wsum[4];
  if (lane == 63) wsum[wv] = incl;
  __syncthreads();
  int woff = 0;
  for (int w = 0; w < wv; ++w) woff += wsum[w];
  int run = woff + incl - tsum;
#pragma unroll
  for (int i = 0; i < 8; ++i) {
    int idx = tbase + i;
    if (idx < N) row_ptr[idx] = run;
    run += vals[i];
  }
  if (threadIdx.x == 255) bsum[blockIdx.x] = woff + incl;
}

__global__ __launch_bounds__(64) void scan2_kernel(
    const int* __restrict__ bsum, int* __restrict__ bpre, int NB) {
  const int lane = threadIdx.x;
  int running = 0;
  for (int c = 0; c < NB; c += 64) {
    int v = (c + lane < NB) ? bsum[c + lane] : 0;
    int incl = v;
#pragma unroll
    for (int off = 1; off < 64; off <<= 1) {
      int nv = __shfl_up(incl, off);
      if (lane >= off) incl += nv;
    }
    if (c + lane < NB) bpre[c + lane] = running + incl - v;
    running += __shfl(incl, 63);
  }
}

__global__ __launch_bounds__(256) void scan3_kernel(
    int* __restrict__ row_ptr, const int* __restrict__ bpre, int N, int E) {
  int t = blockIdx.x * 256 + threadIdx.x;
  if (t < N) row_ptr[t] += bpre[t >> 11];
  if (t == 0) row_ptr[N] = E;
}

__global__ __launch_bounds__(256) void scatter_kernel(
    const int* __restrict__ src, const int* __restrict__ dst,
    const int* __restrict__ row_ptr, int* __restrict__ cursor,
    int* __restrict__ ssorted, int E) {
  int e = blockIdx.x * 256 + threadIdx.x;
  if (e >= E) return;
  int d = dst[e];
  int pos = row_ptr[d] + atomicAdd(&cursor[d], 1);
  ssorted[pos] = src[e];
}

// ============ fused softmax + aggregate (single edge pass) =================
// One wave per node. lane = p*32 + c5: p = edge parity, c5 = col group
// (cols c5*4..c5*4+3, uint2 bf16 gather), head h = c5>>3.
// Straight-line 4-pair (8-edge) body; xor-32 parity combine at end.
// alpha = exp(v)/sum(exp), no max-subtraction (v bounded).

#define PAIR_LOAD(i, e_)                                                    \
  int s##i = ssorted[(e_) + p];                                             \
  float x##i; uint2 fr##i;                                                  \
  {                                                                         \
    float v = el[s##i * HEADS + h] + ern;                                   \
    x##i = __expf(lrelu(v));                                                \
    fr##i = *(const uint2*)&feat[(size_t)s##i * HF + c4];                   \
  }
#define PAIR_ACC(i)                                                         \
  {                                                                         \
    float2 q0 = unpack_bf16(fr##i.x), q1 = unpack_bf16(fr##i.y);            \
    ssum += x##i;                                                           \
    a0 = fmaf(x##i, q0.x, a0); a1 = fmaf(x##i, q0.y, a1);                   \
    a2 = fmaf(x##i, q1.x, a2); a3 = fmaf(x##i, q1.y, a3);                   \
  }

// Layer 1 epilogue: H[n] = elu(inv*agg + res[n] + bias)   (res, H bf16)
__global__ __launch_bounds__(256) void agg1_fused(
    const int* __restrict__ row_ptr, const int* __restrict__ ssorted,
    const float* __restrict__ el, const float* __restrict__ er,
    const bf16* __restrict__ feat, const bf16* __restrict__ res,
    bf16* __restrict__ H, const float* __restrict__ bias, int N) {
  int n = blockIdx.x * 4 + (threadIdx.x >> 6);
  if (n >= N) return;
  const int lane = threadIdx.x & 63;
  const int p = lane >> 5;         // edge parity
  const int c5 = lane & 31;        // col group
  const int c4 = c5 * 4;
  const int h = c5 >> 3;
  const int rb = row_ptr[n], re = row_ptr[n + 1];
  const float ern = er[n * HEADS + h];

  float a0 = 0.f, a1 = 0.f, a2 = 0.f, a3 = 0.f, ssum = 0.f;
  int e = rb;
  for (; e + 7 < re; e += 8) {
    PAIR_LOAD(0, e) PAIR_LOAD(1, e + 2) PAIR_LOAD(2, e + 4) PAIR_LOAD(3, e + 6)
    PAIR_ACC(0) PAIR_ACC(1) PAIR_ACC(2) PAIR_ACC(3)
  }
  for (; e + 3 < re; e += 4) {
    PAIR_LOAD(0, e) PAIR_LOAD(1, e + 2)
    PAIR_ACC(0) PAIR_ACC(1)
  }
  for (; e + 1 < re; e += 2) {
    PAIR_LOAD(0, e)
    PAIR_ACC(0)
  }
  if (e < re && p == 0) {
    int s = ssorted[e];
    float v = el[s * HEADS + h] + ern;
    float x = __expf(lrelu(v));
    uint2 fr = *(const uint2*)&feat[(size_t)s * HF + c4];
    float2 q0 = unpack_bf16(fr.x), q1 = unpack_bf16(fr.y);
    ssum += x;
    a0 = fmaf(x, q0.x, a0); a1 = fmaf(x, q0.y, a1);
    a2 = fmaf(x, q1.x, a2); a3 = fmaf(x, q1.y, a3);
  }
  // parity combine
  a0 += __shfl_xor(a0, 32); a1 += __shfl_xor(a1, 32);
  a2 += __shfl_xor(a2, 32); a3 += __shfl_xor(a3, 32);
  ssum += __shfl_xor(ssum, 32);
  if (lane < 32) {
    float inv = 1.f / ssum;
    uint2 rr = *(const uint2*)&res[(size_t)n * HF + c4];
    float2 r0 = unpack_bf16(rr.x), r1 = unpack_bf16(rr.y);
    float4 bi = *(const float4*)&bias[c4];
    float v0 = fmaf(a0, inv, r0.x + bi.x);
    float v1 = fmaf(a1, inv, r0.y + bi.y);
    float v2 = fmaf(a2, inv, r1.x + bi.z);
    float v3 = fmaf(a3, inv, r1.y + bi.w);
    v0 = (v0 > 0.f) ? v0 : expm1f(v0);
    v1 = (v1 > 0.f) ? v1 : expm1f(v1);
    v2 = (v2 > 0.f) ? v2 : expm1f(v2);
    v3 = (v3 > 0.f) ? v3 : expm1f(v3);
    *(uint2*)&H[(size_t)n * HF + c4] =
        make_uint2(pack_bf16(v0, v1), pack_bf16(v2, v3));
  }
}

// Layer 2 epilogue: head-mean -> sigmoid gate -> readout atomics.
__global__ __launch_bounds__(256) void agg2_fused(
    const int* __restrict__ row_ptr, const int* __restrict__ ssorted,
    const float* __restrict__ el, const float* __restrict__ er,
    const bf16* __restrict__ feat, const bf16* __restrict__ h1,
    const float* __restrict__ bias, const float* __restrict__ ww,
    const float* __restrict__ wb, const int* __restrict__ gids,
    float* __restrict__ hsum, unsigned* __restrict__ hmax, int N) {
  int n = blockIdx.x * 4 + (threadIdx.x >> 6);
  if (n >= N) return;
  const int lane = threadIdx.x & 63;
  const int p = lane >> 5;
  const int c5 = lane & 31;
  const int c4 = c5 * 4;
  const int h = c5 >> 3;
  const int rb = row_ptr[n], re = row_ptr[n + 1];
  const float ern = er[n * HEADS + h];

  float a0 = 0.f, a1 = 0.f, a2 = 0.f, a3 = 0.f, ssum = 0.f;
  int e = rb;
  for (; e + 7 < re; e += 8) {
    PAIR_LOAD(0, e) PAIR_LOAD(1, e + 2) PAIR_LOAD(2, e + 4) PAIR_LOAD(3, e + 6)
    PAIR_ACC(0) PAIR_ACC(1) PAIR_ACC(2) PAIR_ACC(3)
  }
  for (; e + 3 < re; e += 4) {
    PAIR_LOAD(0, e) PAIR_LOAD(1, e + 2)
    PAIR_ACC(0) PAIR_ACC(1)
  }
  for (; e + 1 < re; e += 2) {
    PAIR_LOAD(0, e)
    PAIR_ACC(0)
  }
  if (e < re && p == 0) {
    int s = ssorted[e];
    float v = el[s * HEADS + h] + ern;
    float x = __expf(lrelu(v));
    uint2 fr = *(const uint2*)&feat[(size_t)s * HF + c4];
    float2 q0 = unpack_bf16(fr.x), q1 = unpack_bf16(fr.y);
    ssum += x;
    a0 = fmaf(x, q0.x, a0); a1 = fmaf(x, q0.y, a1);
    a2 = fmaf(x, q1.x, a2); a3 = fmaf(x, q1.y, a3);
  }
  // parity combine
  a0 += __shfl_xor(a0, 32); a1 += __shfl_xor(a1, 32);
  a2 += __shfl_xor(a2, 32); a3 += __shfl_xor(a3, 32);
  ssum += __shfl_xor(ssum, 32);
  if (lane < 32) {
    float inv = 1.f / ssum;
    uint2 rr = *(const uint2*)&h1[(size_t)n * HF + c4];
    float2 r0 = unpack_bf16(rr.x), r1 = unpack_bf16(rr.y);
    float4 bi = *(const float4*)&bias[c4];
    a0 = fmaf(a0, inv, r0.x + bi.x);
    a1 = fmaf(a1, inv, r0.y + bi.y);
    a2 = fmaf(a2, inv, r1.x + bi.z);
    a3 = fmaf(a3, inv, r1.y + bi.w);
    // head mean: lanes c5, c5^8, c5^16, c5^24 hold the 4 heads of same cols
#pragma unroll
    for (int off = 8; off < 32; off <<= 1) {
      a0 += __shfl_xor(a0, off);
      a1 += __shfl_xor(a1, off);
      a2 += __shfl_xor(a2, off);
      a3 += __shfl_xor(a3, off);
    }
    a0 *= 0.25f; a1 *= 0.25f; a2 *= 0.25f; a3 *= 0.25f;
    // sigmoid gate: dot(node_feats, ww) over the 8 col groups
    int f = (c5 & 7) * 4;
    float d = a0 * ww[f] + a1 * ww[f + 1] + a2 * ww[f + 2] + a3 * ww[f + 3];
#pragma unroll
    for (int off = 1; off < 8; off <<= 1) d += __shfl_xor(d, off);
    float wv = 1.f / (1.f + __expf(-(d + wb[0])));
    if (lane < 8) {
      int g = gids[n];
      atomicAdd(&hsum[g * OUTF + f], wv * a0);
      atomicAdd(&hsum[g * OUTF + f + 1], wv * a1);
      atomicAdd(&hsum[g * OUTF + f + 2], wv * a2);
      atomicAdd(&hsum[g * OUTF + f + 3], wv * a3);
      atomicMax(&hmax[g * OUTF + f], enc_f(a0));
      atomicMax(&hmax[g * OUTF + f + 1], enc_f(a1));
      atomicMax(&hmax[g * OUTF + f + 2], enc_f(a2));
      atomicMax(&hmax[g * OUTF + f + 3], enc_f(a3));
    }
  }
}

// ============================ readout tail =================================
__global__ __launch_bounds__(256) void init_readout_kernel(
    float* __restrict__ hsum, unsigned* __restrict__ hmax, int g32) {
  int t = blockIdx.x * 256 + threadIdx.x;
  if (t >= g32) return;
  hsum[t] = 0.f;
  hmax[t] = NEG_INF_ENC;
}

__global__ __launch_bounds__(256) void final_gemm_kernel(
    const float* __restrict__ hsum, const unsigned* __restrict__ hmax,
    const float* __restrict__ tw, const float* __restrict__ tb,
    float* __restrict__ out, int G) {
  __shared__ float tws[64 * PRED_DIM];
  for (int i = threadIdx.x; i < 64 * PRED_DIM; i += 256) tws[i] = tw[i];
  __syncthreads();
  int g = blockIdx.x * 2 + (threadIdx.x >> 7);
  int p = threadIdx.x & 127;
  if (g >= G) return;
  float acc = tb[p];
#pragma unroll
  for (int k = 0; k < OUTF; ++k)
    acc = fmaf(hsum[g * OUTF + k], tws[k * PRED_DIM + p], acc);
#pragma unroll
  for (int k = 0; k < OUTF; ++k)
    acc = fmaf(dec_f(hmax[g * OUTF + k]), tws[(OUTF + k) * PRED_DIM + p], acc);
  out[(size_t)g * PRED_DIM + p] = acc;
}

static inline int cdiv(long long a, int b) { return (int)((a + b - 1) / b); }

extern "C" void kernel_launch(void* const* d_in, const int* in_sizes, int n_in,
                              void* d_out, int out_size, void* d_ws,
                              size_t ws_size, hipStream_t stream) {
  const float* feats   = (const float*)d_in[0];
  const int*   src     = (const int*)d_in[1];
  const int*   dst     = (const int*)d_in[2];
  const int*   gids    = (const int*)d_in[3];
  const float* fc1_w   = (const float*)d_in[4];
  const float* attn_l1 = (const float*)d_in[5];
  const float* attn_r1 = (const float*)d_in[6];
  const float* res1_w  = (const float*)d_in[7];
  const float* bias1   = (const float*)d_in[8];
  const float* fc2_w   = (const float*)d_in[9];
  const float* attn_l2 = (const float*)d_in[10];
  const float* attn_r2 = (const float*)d_in[11];
  const float* bias2   = (const float*)d_in[12];
  const float* ww      = (const float*)d_in[13];
  const float* wb      = (const float*)d_in[14];
  const float* tw      = (const float*)d_in[15];
  const float* tb      = (const float*)d_in[16];
  float* out = (float*)d_out;

  const int N = in_sizes[0] / IN_FEATS;  // 100000
  const int E = in_sizes[1];             // 900000
  const int G = out_size / PRED_DIM;     // 2048
  const int NB = cdiv(N, 2048);

  // ---- workspace layout ----
  bf16* A = (bf16*)d_ws;                      // N*128 bf16 (feat1/feat2)
  bf16* B = A + (size_t)N * HF;               // N*128 bf16 (res1)
  bf16* H = B + (size_t)N * HF;               // N*128 bf16 (h1)
  float* el = (float*)(H + (size_t)N * HF);   // N*4
  float* er = el + (size_t)N * HEADS;         // N*4
  float* hsum = er + (size_t)N * HEADS;       // G*32
  unsigned* hmax = (unsigned*)(hsum + (size_t)G * OUTF);  // G*32
  int* deg     = (int*)(hmax + (size_t)G * OUTF);  // N
  int* cursor  = deg + N;                          // N
  int* row_ptr = cursor + N;                       // N+1
  int* ssorted = row_ptr + (N + 1);                // E
  int* bsum    = ssorted + E;                      // NB
  int* bpre    = bsum + NB;                        // NB

  const int gblk = cdiv(N, 64);
  const int nwblk = cdiv(N, 4);

  // ===================== CSR build =====================
  hipMemsetAsync(deg, 0, (size_t)N * sizeof(int), stream);
  hipMemsetAsync(cursor, 0, (size_t)N * sizeof(int), stream);
  hist_kernel<<<cdiv(E, 256), 256, 0, stream>>>(dst, deg, E);
  scan1_kernel<<<NB, 256, 0, stream>>>(deg, row_ptr, bsum, N);
  scan2_kernel<<<1, 64, 0, stream>>>(bsum, bpre, NB);
  scan3_kernel<<<cdiv(N, 256), 256, 0, stream>>>(row_ptr, bpre, N, E);
  scatter_kernel<<<cdiv(E, 256), 256, 0, stream>>>(src, dst, row_ptr, cursor,
                                                   ssorted, E);

  // ===================== Layer 1 =====================
  gemm_tiled<IN_FEATS, float, true><<<gblk, 256, 0, stream>>>(
      feats, fc1_w, attn_l1, attn_r1, A, el, er, N);
  gemm_tiled<IN_FEATS, float, false><<<gblk, 256, 0, stream>>>(
      feats, res1_w, nullptr, nullptr, B, nullptr, nullptr, N);
  agg1_fused<<<nwblk, 256, 0, stream>>>(row_ptr, ssorted, el, er, A, B, H,
                                        bias1, N);

  // ===================== Layer 2 =====================
  gemm_tiled<HF, bf16, true><<<gblk, 256, 0, stream>>>(
      H, fc2_w, attn_l2, attn_r2, A, el, er, N);
  init_readout_kernel<<<cdiv(G * OUTF, 256), 256, 0, stream>>>(hsum, hmax,
                                                               G * OUTF);
  agg2_fused<<<nwblk, 256, 0, stream>>>(row_ptr, ssorted, el, er, A, H, bias2,
                                        ww, wb, gids, hsum, hmax, N);

  // ===================== Readout =====================
  final_gemm_kernel<<<cdiv(G, 2), 256, 0, stream>>>(hsum, hmax, tw, tb, out, G);
}

// Round 11
// 469.466 us; speedup vs baseline: 1.0423x; 1.0423x over previous
//
#include <hip/hip_runtime.h>
#include <hip/hip_bf16.h>

// ---------------------------------------------------------------------------
// DGL GAT (2-layer, heads=4, out=32) + WeightedSumAndMax readout.
// Round 10: agg kernels reverted to round-8 form (best: 64-lane/4B gathers,
//           8-edge straight-line unroll — r9's wider/fewer requests lost MLP
//           and regressed). New: layer-1 fc1+res1 fused into gemm_dual that
//           stages X once and reuses ONE bs buffer sequentially (24.7KB LDS,
//           unlike r5's 3-buffer 41.5KB failure).
// ---------------------------------------------------------------------------

#define HEADS 4
#define OUTF 32
#define HF 128            // HEADS*OUTF
#define IN_FEATS 74
#define PRED_DIM 128
#define NEG_SLOPE 0.2f
#define NEG_INF_ENC 0x007fffffu   // enc_f(-inf)

typedef __hip_bfloat16 bf16;
typedef __hip_bfloat162 bf16x2;

__device__ __forceinline__ unsigned enc_f(float f) {
  unsigned u = __float_as_uint(f);
  return (u & 0x80000000u) ? ~u : (u | 0x80000000u);
}
__device__ __forceinline__ float dec_f(unsigned k) {
  return (k & 0x80000000u) ? __uint_as_float(k & 0x7fffffffu)
                           : __uint_as_float(~k);
}
__device__ __forceinline__ unsigned pack_bf16(float a, float b) {
  bf16x2 h = __float22bfloat162_rn(make_float2(a, b));
  return *(unsigned*)&h;
}
__device__ __forceinline__ float2 unpack_bf16(unsigned u) {
  bf16x2 h = *(bf16x2*)&u;
  return __bfloat1622float2(h);
}
// leaky_relu(v, 0.2) == max(v, 0.2*v)
__device__ __forceinline__ float lrelu(float v) {
  return fmaxf(v, NEG_SLOPE * v);
}
__device__ __forceinline__ float ld_f(const float* p) { return *p; }
__device__ __forceinline__ float ld_f(const bf16* p) {
  return __bfloat162float(*p);
}

// ========================= node GEMM (single) =============================
// out[n][j] = dot(X[n,:K], W[:K,j]), bf16 output. 64 nodes x 128 cols/block,
// 8x4 per thread. SCORES: fused el/er epilogue.
template <int K, typename XT, bool SCORES>
__global__ __launch_bounds__(256) void gemm_tiled(
    const XT* __restrict__ X, const float* __restrict__ W,
    const float* __restrict__ attn_l, const float* __restrict__ attn_r,
    bf16* __restrict__ out, float* __restrict__ el, float* __restrict__ er,
    int N) {
  constexpr int BK = 32;
  constexpr int APAD = 68;
  __shared__ float as[BK * APAD];
  __shared__ float bs[BK * HF];
  const int tid = threadIdx.x;
  const int tx = tid & 31;
  const int ty = tid >> 5;
  const int j4 = tx * 4;
  const int nb = ty * 8;
  const int n0 = blockIdx.x * 64;

  float acc[8][4] = {};
  for (int k0 = 0; k0 < K; k0 += BK) {
#pragma unroll
    for (int i = 0; i < 8; ++i) {
      int idx = i * 256 + tid;
      int kk = idx & 31, nl = idx >> 5;
      int n = n0 + nl, k = k0 + kk;
      float v = 0.f;
      if (n < N && k < K) v = ld_f(&X[(size_t)n * K + k]);
      as[kk * APAD + nl] = v;
    }
#pragma unroll
    for (int i = 0; i < 16; ++i) {
      int idx = i * 256 + tid;
      int kk = idx >> 7, c = idx & 127;
      int k = k0 + kk;
      bs[idx] = (k < K) ? W[(size_t)k * HF + c] : 0.f;
    }
    __syncthreads();
#pragma unroll 8
    for (int kk = 0; kk < BK; ++kk) {
      float4 wv = *(const float4*)&bs[kk * HF + j4];
      float4 a0 = *(const float4*)&as[kk * APAD + nb];
      float4 a1 = *(const float4*)&as[kk * APAD + nb + 4];
      float av[8] = {a0.x, a0.y, a0.z, a0.w, a1.x, a1.y, a1.z, a1.w};
#pragma unroll
      for (int i = 0; i < 8; ++i) {
        acc[i][0] = fmaf(av[i], wv.x, acc[i][0]);
        acc[i][1] = fmaf(av[i], wv.y, acc[i][1]);
        acc[i][2] = fmaf(av[i], wv.z, acc[i][2]);
        acc[i][3] = fmaf(av[i], wv.w, acc[i][3]);
      }
    }
    __syncthreads();
  }
#pragma unroll
  for (int i = 0; i < 8; ++i) {
    int n = n0 + nb + i;
    if (n < N)
      *(uint2*)&out[(size_t)n * HF + j4] =
          make_uint2(pack_bf16(acc[i][0], acc[i][1]),
                     pack_bf16(acc[i][2], acc[i][3]));
  }
  if (SCORES) {
    float al0 = attn_l[j4], al1 = attn_l[j4 + 1];
    float al2 = attn_l[j4 + 2], al3 = attn_l[j4 + 3];
    float ar0 = attn_r[j4], ar1 = attn_r[j4 + 1];
    float ar2 = attn_r[j4 + 2], ar3 = attn_r[j4 + 3];
    const int h = tx >> 3;
#pragma unroll
    for (int i = 0; i < 8; ++i) {
      float pl = acc[i][0] * al0 + acc[i][1] * al1 +
                 acc[i][2] * al2 + acc[i][3] * al3;
      float pr = acc[i][0] * ar0 + acc[i][1] * ar1 +
                 acc[i][2] * ar2 + acc[i][3] * ar3;
      pl += __shfl_xor(pl, 1); pr += __shfl_xor(pr, 1);
      pl += __shfl_xor(pl, 2); pr += __shfl_xor(pr, 2);
      pl += __shfl_xor(pl, 4); pr += __shfl_xor(pr, 4);
      int n = n0 + nb + i;
      if ((tx & 7) == 0 && n < N) {
        el[n * HEADS + h] = pl;
        er[n * HEADS + h] = pr;
      }
    }
  }
}

// ========================= node GEMM (dual, layer 1) =======================
// fc1 (->outA bf16, + scores epilogue) and res1 (->outB bf16) over the same
// X. X staged ONCE per k-tile; bs reused sequentially for W1 then W2 (same
// LDS footprint as the single-GEMM kernel).
template <int K>
__global__ __launch_bounds__(256) void gemm_dual(
    const float* __restrict__ X, const float* __restrict__ W1,
    const float* __restrict__ W2, const float* __restrict__ attn_l,
    const float* __restrict__ attn_r, bf16* __restrict__ outA,
    bf16* __restrict__ outB, float* __restrict__ el, float* __restrict__ er,
    int N) {
  constexpr int BK = 32;
  constexpr int APAD = 68;
  __shared__ float as[BK * APAD];
  __shared__ float bs[BK * HF];
  const int tid = threadIdx.x;
  const int tx = tid & 31;
  const int ty = tid >> 5;
  const int j4 = tx * 4;
  const int nb = ty * 8;
  const int n0 = blockIdx.x * 64;

  float acc1[8][4] = {};
  float acc2[8][4] = {};
  for (int k0 = 0; k0 < K; k0 += BK) {
#pragma unroll
    for (int i = 0; i < 8; ++i) {
      int idx = i * 256 + tid;
      int kk = idx & 31, nl = idx >> 5;
      int n = n0 + nl, k = k0 + kk;
      float v = 0.f;
      if (n < N && k < K) v = X[(size_t)n * K + k];
      as[kk * APAD + nl] = v;
    }
#pragma unroll
    for (int i = 0; i < 16; ++i) {
      int idx = i * 256 + tid;
      int kk = idx >> 7, c = idx & 127;
      int k = k0 + kk;
      bs[idx] = (k < K) ? W1[(size_t)k * HF + c] : 0.f;
    }
    __syncthreads();
#pragma unroll 8
    for (int kk = 0; kk < BK; ++kk) {
      float4 wv = *(const float4*)&bs[kk * HF + j4];
      float4 a0 = *(const float4*)&as[kk * APAD + nb];
      float4 a1 = *(const float4*)&as[kk * APAD + nb + 4];
      float av[8] = {a0.x, a0.y, a0.z, a0.w, a1.x, a1.y, a1.z, a1.w};
#pragma unroll
      for (int i = 0; i < 8; ++i) {
        acc1[i][0] = fmaf(av[i], wv.x, acc1[i][0]);
        acc1[i][1] = fmaf(av[i], wv.y, acc1[i][1]);
        acc1[i][2] = fmaf(av[i], wv.z, acc1[i][2]);
        acc1[i][3] = fmaf(av[i], wv.w, acc1[i][3]);
      }
    }
    __syncthreads();
#pragma unroll
    for (int i = 0; i < 16; ++i) {
      int idx = i * 256 + tid;
      int kk = idx >> 7, c = idx & 127;
      int k = k0 + kk;
      bs[idx] = (k < K) ? W2[(size_t)k * HF + c] : 0.f;
    }
    __syncthreads();
#pragma unroll 8
    for (int kk = 0; kk < BK; ++kk) {
      float4 wv = *(const float4*)&bs[kk * HF + j4];
      float4 a0 = *(const float4*)&as[kk * APAD + nb];
      float4 a1 = *(const float4*)&as[kk * APAD + nb + 4];
      float av[8] = {a0.x, a0.y, a0.z, a0.w, a1.x, a1.y, a1.z, a1.w};
#pragma unroll
      for (int i = 0; i < 8; ++i) {
        acc2[i][0] = fmaf(av[i], wv.x, acc2[i][0]);
        acc2[i][1] = fmaf(av[i], wv.y, acc2[i][1]);
        acc2[i][2] = fmaf(av[i], wv.z, acc2[i][2]);
        acc2[i][3] = fmaf(av[i], wv.w, acc2[i][3]);
      }
    }
    __syncthreads();
  }
#pragma unroll
  for (int i = 0; i < 8; ++i) {
    int n = n0 + nb + i;
    if (n < N) {
      *(uint2*)&outA[(size_t)n * HF + j4] =
          make_uint2(pack_bf16(acc1[i][0], acc1[i][1]),
                     pack_bf16(acc1[i][2], acc1[i][3]));
      *(uint2*)&outB[(size_t)n * HF + j4] =
          make_uint2(pack_bf16(acc2[i][0], acc2[i][1]),
                     pack_bf16(acc2[i][2], acc2[i][3]));
    }
  }
  // scores from acc1 (fc1 output)
  {
    float al0 = attn_l[j4], al1 = attn_l[j4 + 1];
    float al2 = attn_l[j4 + 2], al3 = attn_l[j4 + 3];
    float ar0 = attn_r[j4], ar1 = attn_r[j4 + 1];
    float ar2 = attn_r[j4 + 2], ar3 = attn_r[j4 + 3];
    const int h = tx >> 3;
#pragma unroll
    for (int i = 0; i < 8; ++i) {
      float pl = acc1[i][0] * al0 + acc1[i][1] * al1 +
                 acc1[i][2] * al2 + acc1[i][3] * al3;
      float pr = acc1[i][0] * ar0 + acc1[i][1] * ar1 +
                 acc1[i][2] * ar2 + acc1[i][3] * ar3;
      pl += __shfl_xor(pl, 1); pr += __shfl_xor(pr, 1);
      pl += __shfl_xor(pl, 2); pr += __shfl_xor(pr, 2);
      pl += __shfl_xor(pl, 4); pr += __shfl_xor(pr, 4);
      int n = n0 + nb + i;
      if ((tx & 7) == 0 && n < N) {
        el[n * HEADS + h] = pl;
        er[n * HEADS + h] = pr;
      }
    }
  }
}

// ============================ CSR build ====================================
__global__ __launch_bounds__(256) void hist_kernel(
    const int* __restrict__ dst, int* __restrict__ deg, int E) {
  int e = blockIdx.x * 256 + threadIdx.x;
  if (e < E) atomicAdd(&deg[dst[e]], 1);
}

__global__ __launch_bounds__(256) void scan1_kernel(
    const int* __restrict__ deg, int* __restrict__ row_ptr,
    int* __restrict__ bsum, int N) {
  const int base = blockIdx.x * 2048;
  const int tbase = base + threadIdx.x * 8;
  int vals[8];
  int tsum = 0;
#pragma unroll
  for (int i = 0; i < 8; ++i) {
    int idx = tbase + i;
    vals[i] = (idx < N) ? deg[idx] : 0;
    tsum += vals[i];
  }
  const int lane = threadIdx.x & 63, wv = threadIdx.x >> 6;
  int incl = tsum;
#pragma unroll
  for (int off = 1; off < 64; off <<= 1) {
    int nv = __shfl_up(incl, off);
    if (lane >= off) incl += nv;
  }
  __shared__ int wsum[4];
  if (lane == 63) wsum[wv] = incl;
  __syncthreads();
  int woff = 0;
  for (int w = 0; w < wv; ++w) woff += wsum[w];
  int run = woff + incl - tsum;
#pragma unroll
  for (int i = 0; i < 8; ++i) {
    int idx = tbase + i;
    if (idx < N) row_ptr[idx] = run;
    run += vals[i];
  }
  if (threadIdx.x == 255) bsum[blockIdx.x] = woff + incl;
}

__global__ __launch_bounds__(64) void scan2_kernel(
    const int* __restrict__ bsum, int* __restrict__ bpre, int NB) {
  const int lane = threadIdx.x;
  int running = 0;
  for (int c = 0; c < NB; c += 64) {
    int v = (c + lane < NB) ? bsum[c + lane] : 0;
    int incl = v;
#pragma unroll
    for (int off = 1; off < 64; off <<= 1) {
      int nv = __shfl_up(incl, off);
      if (lane >= off) incl += nv;
    }
    if (c + lane < NB) bpre[c + lane] = running + incl - v;
    running += __shfl(incl, 63);
  }
}

__global__ __launch_bounds__(256) void scan3_kernel(
    int* __restrict__ row_ptr, const int* __restrict__ bpre, int N, int E) {
  int t = blockIdx.x * 256 + threadIdx.x;
  if (t < N) row_ptr[t] += bpre[t >> 11];
  if (t == 0) row_ptr[N] = E;
}

__global__ __launch_bounds__(256) void scatter_kernel(
    const int* __restrict__ src, const int* __restrict__ dst,
    const int* __restrict__ row_ptr, int* __restrict__ cursor,
    int* __restrict__ ssorted, int E) {
  int e = blockIdx.x * 256 + threadIdx.x;
  if (e >= E) return;
  int d = dst[e];
  int pos = row_ptr[d] + atomicAdd(&cursor[d], 1);
  ssorted[pos] = src[e];
}

// ============ fused softmax + aggregate (single edge pass) =================
// One wave per node; lane holds cols (2*lane, 2*lane+1), head h = lane>>4.
// 8-edge straight-line unroll (~24 loads in flight), 4-edge + scalar tails.
// alpha = exp(v)/sum(exp), no max-subtraction (v bounded).    [round-8 form]

#define EDGE_LOAD(i, e_)                                                    \
  int s##i = ssorted[e_];                                                   \
  float x##i; float2 f##i;                                                  \
  {                                                                         \
    float v = el[s##i * HEADS + h] + ern;                                   \
    x##i = __expf(lrelu(v));                                                \
    f##i = unpack_bf16(*(const unsigned*)&feat[(size_t)s##i * HF + c2]);    \
  }
#define EDGE_ACC(i)                                                         \
  ssum += x##i;                                                             \
  ax = fmaf(x##i, f##i.x, ax);                                              \
  ay = fmaf(x##i, f##i.y, ay);

// Layer 1 epilogue: H[n] = elu(inv*agg + res[n] + bias)   (res, H bf16)
__global__ __launch_bounds__(256) void agg1_fused(
    const int* __restrict__ row_ptr, const int* __restrict__ ssorted,
    const float* __restrict__ el, const float* __restrict__ er,
    const bf16* __restrict__ feat, const bf16* __restrict__ res,
    bf16* __restrict__ H, const float* __restrict__ bias, int N) {
  int n = blockIdx.x * 4 + (threadIdx.x >> 6);
  if (n >= N) return;
  const int lane = threadIdx.x & 63;
  const int c2 = lane * 2, h = lane >> 4;
  const int rb = row_ptr[n], re = row_ptr[n + 1];
  const float ern = er[n * HEADS + h];

  float ax = 0.f, ay = 0.f, ssum = 0.f;
  int e = rb;
  for (; e + 7 < re; e += 8) {
    EDGE_LOAD(0, e) EDGE_LOAD(1, e + 1) EDGE_LOAD(2, e + 2)
    EDGE_LOAD(3, e + 3) EDGE_LOAD(4, e + 4) EDGE_LOAD(5, e + 5)
    EDGE_LOAD(6, e + 6) EDGE_LOAD(7, e + 7)
    EDGE_ACC(0) EDGE_ACC(1) EDGE_ACC(2) EDGE_ACC(3)
    EDGE_ACC(4) EDGE_ACC(5) EDGE_ACC(6) EDGE_ACC(7)
  }
  for (; e + 3 < re; e += 4) {
    EDGE_LOAD(0, e) EDGE_LOAD(1, e + 1) EDGE_LOAD(2, e + 2)
    EDGE_LOAD(3, e + 3)
    EDGE_ACC(0) EDGE_ACC(1) EDGE_ACC(2) EDGE_ACC(3)
  }
  for (; e < re; ++e) {
    EDGE_LOAD(0, e)
    EDGE_ACC(0)
  }
  float inv = 1.f / ssum;
  float2 r = unpack_bf16(*(const unsigned*)&res[(size_t)n * HF + c2]);
  float2 bi = *(const float2*)&bias[c2];
  float vx = fmaf(ax, inv, r.x + bi.x);
  float vy = fmaf(ay, inv, r.y + bi.y);
  vx = (vx > 0.f) ? vx : expm1f(vx);
  vy = (vy > 0.f) ? vy : expm1f(vy);
  *(unsigned*)&H[(size_t)n * HF + c2] = pack_bf16(vx, vy);
}

// Layer 2 epilogue: head-mean -> sigmoid gate -> readout atomics.
__global__ __launch_bounds__(256) void agg2_fused(
    const int* __restrict__ row_ptr, const int* __restrict__ ssorted,
    const float* __restrict__ el, const float* __restrict__ er,
    const bf16* __restrict__ feat, const bf16* __restrict__ h1,
    const float* __restrict__ bias, const float* __restrict__ ww,
    const float* __restrict__ wb, const int* __restrict__ gids,
    float* __restrict__ hsum, unsigned* __restrict__ hmax, int N) {
  int n = blockIdx.x * 4 + (threadIdx.x >> 6);
  if (n >= N) return;
  const int lane = threadIdx.x & 63;
  const int c2 = lane * 2, h = lane >> 4;
  const int rb = row_ptr[n], re = row_ptr[n + 1];
  const float ern = er[n * HEADS + h];

  float ax = 0.f, ay = 0.f, ssum = 0.f;
  int e = rb;
  for (; e + 7 < re; e += 8) {
    EDGE_LOAD(0, e) EDGE_LOAD(1, e + 1) EDGE_LOAD(2, e + 2)
    EDGE_LOAD(3, e + 3) EDGE_LOAD(4, e + 4) EDGE_LOAD(5, e + 5)
    EDGE_LOAD(6, e + 6) EDGE_LOAD(7, e + 7)
    EDGE_ACC(0) EDGE_ACC(1) EDGE_ACC(2) EDGE_ACC(3)
    EDGE_ACC(4) EDGE_ACC(5) EDGE_ACC(6) EDGE_ACC(7)
  }
  for (; e + 3 < re; e += 4) {
    EDGE_LOAD(0, e) EDGE_LOAD(1, e + 1) EDGE_LOAD(2, e + 2)
    EDGE_LOAD(3, e + 3)
    EDGE_ACC(0) EDGE_ACC(1) EDGE_ACC(2) EDGE_ACC(3)
  }
  for (; e < re; ++e) {
    EDGE_LOAD(0, e)
    EDGE_ACC(0)
  }
  float inv = 1.f / ssum;
  float2 r = unpack_bf16(*(const unsigned*)&h1[(size_t)n * HF + c2]);
  float2 bi = *(const float2*)&bias[c2];
  ax = fmaf(ax, inv, r.x + bi.x);
  ay = fmaf(ay, inv, r.y + bi.y);
  // head mean: after xor 16,32 every lane holds the sum over its 4-head class
#pragma unroll
  for (int off = 16; off < 64; off <<= 1) {
    ax += __shfl_xor(ax, off);
    ay += __shfl_xor(ay, off);
  }
  ax *= 0.25f;
  ay *= 0.25f;
  // sigmoid gate: dot(node_feats, ww) reduced over the 16-lane col groups
  int c = c2 & 31;
  float d = fmaf(ax, ww[c], ay * ww[c + 1]);
#pragma unroll
  for (int off = 1; off < 16; off <<= 1) d += __shfl_xor(d, off);
  float wv = 1.f / (1.f + __expf(-(d + wb[0])));
  if (lane < 16) {
    int g = gids[n];
    atomicAdd(&hsum[g * OUTF + c], wv * ax);
    atomicAdd(&hsum[g * OUTF + c + 1], wv * ay);
    atomicMax(&hmax[g * OUTF + c], enc_f(ax));
    atomicMax(&hmax[g * OUTF + c + 1], enc_f(ay));
  }
}

// ============================ readout tail =================================
__global__ __launch_bounds__(256) void init_readout_kernel(
    float* __restrict__ hsum, unsigned* __restrict__ hmax, int g32) {
  int t = blockIdx.x * 256 + threadIdx.x;
  if (t >= g32) return;
  hsum[t] = 0.f;
  hmax[t] = NEG_INF_ENC;
}

__global__ __launch_bounds__(256) void final_gemm_kernel(
    const float* __restrict__ hsum, const unsigned* __restrict__ hmax,
    const float* __restrict__ tw, const float* __restrict__ tb,
    float* __restrict__ out, int G) {
  __shared__ float tws[64 * PRED_DIM];
  for (int i = threadIdx.x; i < 64 * PRED_DIM; i += 256) tws[i] = tw[i];
  __syncthreads();
  int g = blockIdx.x * 2 + (threadIdx.x >> 7);
  int p = threadIdx.x & 127;
  if (g >= G) return;
  float acc = tb[p];
#pragma unroll
  for (int k = 0; k < OUTF; ++k)
    acc = fmaf(hsum[g * OUTF + k], tws[k * PRED_DIM + p], acc);
#pragma unroll
  for (int k = 0; k < OUTF; ++k)
    acc = fmaf(dec_f(hmax[g * OUTF + k]), tws[(OUTF + k) * PRED_DIM + p], acc);
  out[(size_t)g * PRED_DIM + p] = acc;
}

static inline int cdiv(long long a, int b) { return (int)((a + b - 1) / b); }

extern "C" void kernel_launch(void* const* d_in, const int* in_sizes, int n_in,
                              void* d_out, int out_size, void* d_ws,
                              size_t ws_size, hipStream_t stream) {
  const float* feats   = (const float*)d_in[0];
  const int*   src     = (const int*)d_in[1];
  const int*   dst     = (const int*)d_in[2];
  const int*   gids    = (const int*)d_in[3];
  const float* fc1_w   = (const float*)d_in[4];
  const float* attn_l1 = (const float*)d_in[5];
  const float* attn_r1 = (const float*)d_in[6];
  const float* res1_w  = (const float*)d_in[7];
  const float* bias1   = (const float*)d_in[8];
  const float* fc2_w   = (const float*)d_in[9];
  const float* attn_l2 = (const float*)d_in[10];
  const float* attn_r2 = (const float*)d_in[11];
  const float* bias2   = (const float*)d_in[12];
  const float* ww      = (const float*)d_in[13];
  const float* wb      = (const float*)d_in[14];
  const float* tw      = (const float*)d_in[15];
  const float* tb      = (const float*)d_in[16];
  float* out = (float*)d_out;

  const int N = in_sizes[0] / IN_FEATS;  // 100000
  const int E = in_sizes[1];             // 900000
  const int G = out_size / PRED_DIM;     // 2048
  const int NB = cdiv(N, 2048);

  // ---- workspace layout ----
  bf16* A = (bf16*)d_ws;                      // N*128 bf16 (feat1/feat2)
  bf16* B = A + (size_t)N * HF;               // N*128 bf16 (res1)
  bf16* H = B + (size_t)N * HF;               // N*128 bf16 (h1)
  float* el = (float*)(H + (size_t)N * HF);   // N*4
  float* er = el + (size_t)N * HEADS;         // N*4
  float* hsum = er + (size_t)N * HEADS;       // G*32
  unsigned* hmax = (unsigned*)(hsum + (size_t)G * OUTF);  // G*32
  int* deg     = (int*)(hmax + (size_t)G * OUTF);  // N
  int* cursor  = deg + N;                          // N
  int* row_ptr = cursor + N;                       // N+1
  int* ssorted = row_ptr + (N + 1);                // E
  int* bsum    = ssorted + E;                      // NB
  int* bpre    = bsum + NB;                        // NB

  const int gblk = cdiv(N, 64);
  const int nwblk = cdiv(N, 4);

  // ===================== CSR build =====================
  hipMemsetAsync(deg, 0, (size_t)N * sizeof(int), stream);
  hipMemsetAsync(cursor, 0, (size_t)N * sizeof(int), stream);
  hist_kernel<<<cdiv(E, 256), 256, 0, stream>>>(dst, deg, E);
  scan1_kernel<<<NB, 256, 0, stream>>>(deg, row_ptr, bsum, N);
  scan2_kernel<<<1, 64, 0, stream>>>(bsum, bpre, NB);
  scan3_kernel<<<cdiv(N, 256), 256, 0, stream>>>(row_ptr, bpre, N, E);
  scatter_kernel<<<cdiv(E, 256), 256, 0, stream>>>(src, dst, row_ptr, cursor,
                                                   ssorted, E);

  // ===================== Layer 1 =====================
  gemm_dual<IN_FEATS><<<gblk, 256, 0, stream>>>(
      feats, fc1_w, res1_w, attn_l1, attn_r1, A, B, el, er, N);
  agg1_fused<<<nwblk, 256, 0, stream>>>(row_ptr, ssorted, el, er, A, B, H,
                                        bias1, N);

  // ===================== Layer 2 =====================
  gemm_tiled<HF, bf16, true><<<gblk, 256, 0, stream>>>(
      H, fc2_w, attn_l2, attn_r2, A, el, er, N);
  init_readout_kernel<<<cdiv(G * OUTF, 256), 256, 0, stream>>>(hsum, hmax,
                                                               G * OUTF);
  agg2_fused<<<nwblk, 256, 0, stream>>>(row_ptr, ssorted, el, er, A, H, bias2,
                                        ww, wb, gids, hsum, hmax, N);

  // ===================== Readout =====================
  final_gemm_kernel<<<cdiv(G, 2), 256, 0, stream>>>(hsum, hmax, tw, tb, out, G);
}

// Round 12
// 463.444 us; speedup vs baseline: 1.0558x; 1.0130x over previous
//
#include <hip/hip_runtime.h>
#include <hip/hip_bf16.h>

// ---------------------------------------------------------------------------
// DGL GAT (2-layer, heads=4, out=32) + WeightedSumAndMax readout.
// Round 11: GEMM LDS fix — APAD 68->66 kills the 4-way bank conflict on the
//           as[] transpose staging (stride 4 -> 2 banks; 2-way is free);
//           as reads become float2 broadcasts. gemm_dual: two bs buffers,
//           one barrier pair per tile, interleaved W1/W2 FMAs (2x ILP).
//           Agg kernels frozen at round-8 form (best known).
// ---------------------------------------------------------------------------

#define HEADS 4
#define OUTF 32
#define HF 128            // HEADS*OUTF
#define IN_FEATS 74
#define PRED_DIM 128
#define NEG_SLOPE 0.2f
#define NEG_INF_ENC 0x007fffffu   // enc_f(-inf)

typedef __hip_bfloat16 bf16;
typedef __hip_bfloat162 bf16x2;

__device__ __forceinline__ unsigned enc_f(float f) {
  unsigned u = __float_as_uint(f);
  return (u & 0x80000000u) ? ~u : (u | 0x80000000u);
}
__device__ __forceinline__ float dec_f(unsigned k) {
  return (k & 0x80000000u) ? __uint_as_float(k & 0x7fffffffu)
                           : __uint_as_float(~k);
}
__device__ __forceinline__ unsigned pack_bf16(float a, float b) {
  bf16x2 h = __float22bfloat162_rn(make_float2(a, b));
  return *(unsigned*)&h;
}
__device__ __forceinline__ float2 unpack_bf16(unsigned u) {
  bf16x2 h = *(bf16x2*)&u;
  return __bfloat1622float2(h);
}
// leaky_relu(v, 0.2) == max(v, 0.2*v)
__device__ __forceinline__ float lrelu(float v) {
  return fmaxf(v, NEG_SLOPE * v);
}
__device__ __forceinline__ float ld_f(const float* p) { return *p; }
__device__ __forceinline__ float ld_f(const bf16* p) {
  return __bfloat162float(*p);
}

// ========================= node GEMM (single) =============================
// out[n][j] = dot(X[n,:K], W[:K,j]), bf16 output. 64 nodes x 128 cols/block,
// 8x4 per thread. SCORES: fused el/er epilogue.
// APAD=66: bank stride 2 on staging writes (2-way aliasing = free).
template <int K, typename XT, bool SCORES>
__global__ __launch_bounds__(256) void gemm_tiled(
    const XT* __restrict__ X, const float* __restrict__ W,
    const float* __restrict__ attn_l, const float* __restrict__ attn_r,
    bf16* __restrict__ out, float* __restrict__ el, float* __restrict__ er,
    int N) {
  constexpr int BK = 32;
  constexpr int APAD = 66;
  __shared__ float as[BK * APAD];
  __shared__ float bs[BK * HF];
  const int tid = threadIdx.x;
  const int tx = tid & 31;
  const int ty = tid >> 5;
  const int j4 = tx * 4;
  const int nb = ty * 8;
  const int n0 = blockIdx.x * 64;

  float acc[8][4] = {};
  for (int k0 = 0; k0 < K; k0 += BK) {
#pragma unroll
    for (int i = 0; i < 8; ++i) {
      int idx = i * 256 + tid;
      int kk = idx & 31, nl = idx >> 5;
      int n = n0 + nl, k = k0 + kk;
      float v = 0.f;
      if (n < N && k < K) v = ld_f(&X[(size_t)n * K + k]);
      as[kk * APAD + nl] = v;
    }
#pragma unroll
    for (int i = 0; i < 16; ++i) {
      int idx = i * 256 + tid;
      int kk = idx >> 7, c = idx & 127;
      int k = k0 + kk;
      bs[idx] = (k < K) ? W[(size_t)k * HF + c] : 0.f;
    }
    __syncthreads();
#pragma unroll 8
    for (int kk = 0; kk < BK; ++kk) {
      float4 wv = *(const float4*)&bs[kk * HF + j4];
      float2 a01 = *(const float2*)&as[kk * APAD + nb];
      float2 a23 = *(const float2*)&as[kk * APAD + nb + 2];
      float2 a45 = *(const float2*)&as[kk * APAD + nb + 4];
      float2 a67 = *(const float2*)&as[kk * APAD + nb + 6];
      float av[8] = {a01.x, a01.y, a23.x, a23.y, a45.x, a45.y, a67.x, a67.y};
#pragma unroll
      for (int i = 0; i < 8; ++i) {
        acc[i][0] = fmaf(av[i], wv.x, acc[i][0]);
        acc[i][1] = fmaf(av[i], wv.y, acc[i][1]);
        acc[i][2] = fmaf(av[i], wv.z, acc[i][2]);
        acc[i][3] = fmaf(av[i], wv.w, acc[i][3]);
      }
    }
    __syncthreads();
  }
#pragma unroll
  for (int i = 0; i < 8; ++i) {
    int n = n0 + nb + i;
    if (n < N)
      *(uint2*)&out[(size_t)n * HF + j4] =
          make_uint2(pack_bf16(acc[i][0], acc[i][1]),
                     pack_bf16(acc[i][2], acc[i][3]));
  }
  if (SCORES) {
    float al0 = attn_l[j4], al1 = attn_l[j4 + 1];
    float al2 = attn_l[j4 + 2], al3 = attn_l[j4 + 3];
    float ar0 = attn_r[j4], ar1 = attn_r[j4 + 1];
    float ar2 = attn_r[j4 + 2], ar3 = attn_r[j4 + 3];
    const int h = tx >> 3;
#pragma unroll
    for (int i = 0; i < 8; ++i) {
      float pl = acc[i][0] * al0 + acc[i][1] * al1 +
                 acc[i][2] * al2 + acc[i][3] * al3;
      float pr = acc[i][0] * ar0 + acc[i][1] * ar1 +
                 acc[i][2] * ar2 + acc[i][3] * ar3;
      pl += __shfl_xor(pl, 1); pr += __shfl_xor(pr, 1);
      pl += __shfl_xor(pl, 2); pr += __shfl_xor(pr, 2);
      pl += __shfl_xor(pl, 4); pr += __shfl_xor(pr, 4);
      int n = n0 + nb + i;
      if ((tx & 7) == 0 && n < N) {
        el[n * HEADS + h] = pl;
        er[n * HEADS + h] = pr;
      }
    }
  }
}

// ========================= node GEMM (dual, layer 1) =======================
// fc1 (->outA bf16, + scores epilogue) and res1 (->outB bf16) over the same
// X. X + both weight tiles staged once per k-tile (one barrier pair);
// W1/W2 FMAs interleaved in one kk loop (2x independent chains).
// LDS = 8.4K as + 2x16K bs = 41K -> 3 blocks/CU.
template <int K>
__global__ __launch_bounds__(256) void gemm_dual(
    const float* __restrict__ X, const float* __restrict__ W1,
    const float* __restrict__ W2, const float* __restrict__ attn_l,
    const float* __restrict__ attn_r, bf16* __restrict__ outA,
    bf16* __restrict__ outB, float* __restrict__ el, float* __restrict__ er,
    int N) {
  constexpr int BK = 32;
  constexpr int APAD = 66;
  __shared__ float as[BK * APAD];
  __shared__ float bs1[BK * HF];
  __shared__ float bs2[BK * HF];
  const int tid = threadIdx.x;
  const int tx = tid & 31;
  const int ty = tid >> 5;
  const int j4 = tx * 4;
  const int nb = ty * 8;
  const int n0 = blockIdx.x * 64;

  float acc1[8][4] = {};
  float acc2[8][4] = {};
  for (int k0 = 0; k0 < K; k0 += BK) {
#pragma unroll
    for (int i = 0; i < 8; ++i) {
      int idx = i * 256 + tid;
      int kk = idx & 31, nl = idx >> 5;
      int n = n0 + nl, k = k0 + kk;
      float v = 0.f;
      if (n < N && k < K) v = X[(size_t)n * K + k];
      as[kk * APAD + nl] = v;
    }
#pragma unroll
    for (int i = 0; i < 16; ++i) {
      int idx = i * 256 + tid;
      int kk = idx >> 7, c = idx & 127;
      int k = k0 + kk;
      float w1 = 0.f, w2 = 0.f;
      if (k < K) {
        w1 = W1[(size_t)k * HF + c];
        w2 = W2[(size_t)k * HF + c];
      }
      bs1[idx] = w1;
      bs2[idx] = w2;
    }
    __syncthreads();
#pragma unroll 4
    for (int kk = 0; kk < BK; ++kk) {
      float4 w1 = *(const float4*)&bs1[kk * HF + j4];
      float4 w2 = *(const float4*)&bs2[kk * HF + j4];
      float2 a01 = *(const float2*)&as[kk * APAD + nb];
      float2 a23 = *(const float2*)&as[kk * APAD + nb + 2];
      float2 a45 = *(const float2*)&as[kk * APAD + nb + 4];
      float2 a67 = *(const float2*)&as[kk * APAD + nb + 6];
      float av[8] = {a01.x, a01.y, a23.x, a23.y, a45.x, a45.y, a67.x, a67.y};
#pragma unroll
      for (int i = 0; i < 8; ++i) {
        acc1[i][0] = fmaf(av[i], w1.x, acc1[i][0]);
        acc1[i][1] = fmaf(av[i], w1.y, acc1[i][1]);
        acc1[i][2] = fmaf(av[i], w1.z, acc1[i][2]);
        acc1[i][3] = fmaf(av[i], w1.w, acc1[i][3]);
        acc2[i][0] = fmaf(av[i], w2.x, acc2[i][0]);
        acc2[i][1] = fmaf(av[i], w2.y, acc2[i][1]);
        acc2[i][2] = fmaf(av[i], w2.z, acc2[i][2]);
        acc2[i][3] = fmaf(av[i], w2.w, acc2[i][3]);
      }
    }
    __syncthreads();
  }
#pragma unroll
  for (int i = 0; i < 8; ++i) {
    int n = n0 + nb + i;
    if (n < N) {
      *(uint2*)&outA[(size_t)n * HF + j4] =
          make_uint2(pack_bf16(acc1[i][0], acc1[i][1]),
                     pack_bf16(acc1[i][2], acc1[i][3]));
      *(uint2*)&outB[(size_t)n * HF + j4] =
          make_uint2(pack_bf16(acc2[i][0], acc2[i][1]),
                     pack_bf16(acc2[i][2], acc2[i][3]));
    }
  }
  // scores from acc1 (fc1 output)
  {
    float al0 = attn_l[j4], al1 = attn_l[j4 + 1];
    float al2 = attn_l[j4 + 2], al3 = attn_l[j4 + 3];
    float ar0 = attn_r[j4], ar1 = attn_r[j4 + 1];
    float ar2 = attn_r[j4 + 2], ar3 = attn_r[j4 + 3];
    const int h = tx >> 3;
#pragma unroll
    for (int i = 0; i < 8; ++i) {
      float pl = acc1[i][0] * al0 + acc1[i][1] * al1 +
                 acc1[i][2] * al2 + acc1[i][3] * al3;
      float pr = acc1[i][0] * ar0 + acc1[i][1] * ar1 +
                 acc1[i][2] * ar2 + acc1[i][3] * ar3;
      pl += __shfl_xor(pl, 1); pr += __shfl_xor(pr, 1);
      pl += __shfl_xor(pl, 2); pr += __shfl_xor(pr, 2);
      pl += __shfl_xor(pl, 4); pr += __shfl_xor(pr, 4);
      int n = n0 + nb + i;
      if ((tx & 7) == 0 && n < N) {
        el[n * HEADS + h] = pl;
        er[n * HEADS + h] = pr;
      }
    }
  }
}

// ============================ CSR build ====================================
__global__ __launch_bounds__(256) void hist_kernel(
    const int* __restrict__ dst, int* __restrict__ deg, int E) {
  int e = blockIdx.x * 256 + threadIdx.x;
  if (e < E) atomicAdd(&deg[dst[e]], 1);
}

__global__ __launch_bounds__(256) void scan1_kernel(
    const int* __restrict__ deg, int* __restrict__ row_ptr,
    int* __restrict__ bsum, int N) {
  const int base = blockIdx.x * 2048;
  const int tbase = base + threadIdx.x * 8;
  int vals[8];
  int tsum = 0;
#pragma unroll
  for (int i = 0; i < 8; ++i) {
    int idx = tbase + i;
    vals[i] = (idx < N) ? deg[idx] : 0;
    tsum += vals[i];
  }
  const int lane = threadIdx.x & 63, wv = threadIdx.x >> 6;
  int incl = tsum;
#pragma unroll
  for (int off = 1; off < 64; off <<= 1) {
    int nv = __shfl_up(incl, off);
    if (lane >= off) incl += nv;
  }
  __shared__ int wsum[4];
  if (lane == 63) wsum[wv] = incl;
  __syncthreads();
  int woff = 0;
  for (int w = 0; w < wv; ++w) woff += wsum[w];
  int run = woff + incl - tsum;
#pragma unroll
  for (int i = 0; i < 8; ++i) {
    int idx = tbase + i;
    if (idx < N) row_ptr[idx] = run;
    run += vals[i];
  }
  if (threadIdx.x == 255) bsum[blockIdx.x] = woff + incl;
}

__global__ __launch_bounds__(64) void scan2_kernel(
    const int* __restrict__ bsum, int* __restrict__ bpre, int NB) {
  const int lane = threadIdx.x;
  int running = 0;
  for (int c = 0; c < NB; c += 64) {
    int v = (c + lane < NB) ? bsum[c + lane] : 0;
    int incl = v;
#pragma unroll
    for (int off = 1; off < 64; off <<= 1) {
      int nv = __shfl_up(incl, off);
      if (lane >= off) incl += nv;
    }
    if (c + lane < NB) bpre[c + lane] = running + incl - v;
    running += __shfl(incl, 63);
  }
}

__global__ __launch_bounds__(256) void scan3_kernel(
    int* __restrict__ row_ptr, const int* __restrict__ bpre, int N, int E) {
  int t = blockIdx.x * 256 + threadIdx.x;
  if (t < N) row_ptr[t] += bpre[t >> 11];
  if (t == 0) row_ptr[N] = E;
}

__global__ __launch_bounds__(256) void scatter_kernel(
    const int* __restrict__ src, const int* __restrict__ dst,
    const int* __restrict__ row_ptr, int* __restrict__ cursor,
    int* __restrict__ ssorted, int E) {
  int e = blockIdx.x * 256 + threadIdx.x;
  if (e >= E) return;
  int d = dst[e];
  int pos = row_ptr[d] + atomicAdd(&cursor[d], 1);
  ssorted[pos] = src[e];
}

// ============ fused softmax + aggregate (single edge pass) =================
// One wave per node; lane holds cols (2*lane, 2*lane+1), head h = lane>>4.
// 8-edge straight-line unroll (~24 loads in flight), 4-edge + scalar tails.
// alpha = exp(v)/sum(exp), no max-subtraction (v bounded).    [round-8 form]

#define EDGE_LOAD(i, e_)                                                    \
  int s##i = ssorted[e_];                                                   \
  float x##i; float2 f##i;                                                  \
  {                                                                         \
    float v = el[s##i * HEADS + h] + ern;                                   \
    x##i = __expf(lrelu(v));                                                \
    f##i = unpack_bf16(*(const unsigned*)&feat[(size_t)s##i * HF + c2]);    \
  }
#define EDGE_ACC(i)                                                         \
  ssum += x##i;                                                             \
  ax = fmaf(x##i, f##i.x, ax);                                              \
  ay = fmaf(x##i, f##i.y, ay);

// Layer 1 epilogue: H[n] = elu(inv*agg + res[n] + bias)   (res, H bf16)
__global__ __launch_bounds__(256) void agg1_fused(
    const int* __restrict__ row_ptr, const int* __restrict__ ssorted,
    const float* __restrict__ el, const float* __restrict__ er,
    const bf16* __restrict__ feat, const bf16* __restrict__ res,
    bf16* __restrict__ H, const float* __restrict__ bias, int N) {
  int n = blockIdx.x * 4 + (threadIdx.x >> 6);
  if (n >= N) return;
  const int lane = threadIdx.x & 63;
  const int c2 = lane * 2, h = lane >> 4;
  const int rb = row_ptr[n], re = row_ptr[n + 1];
  const float ern = er[n * HEADS + h];

  float ax = 0.f, ay = 0.f, ssum = 0.f;
  int e = rb;
  for (; e + 7 < re; e += 8) {
    EDGE_LOAD(0, e) EDGE_LOAD(1, e + 1) EDGE_LOAD(2, e + 2)
    EDGE_LOAD(3, e + 3) EDGE_LOAD(4, e + 4) EDGE_LOAD(5, e + 5)
    EDGE_LOAD(6, e + 6) EDGE_LOAD(7, e + 7)
    EDGE_ACC(0) EDGE_ACC(1) EDGE_ACC(2) EDGE_ACC(3)
    EDGE_ACC(4) EDGE_ACC(5) EDGE_ACC(6) EDGE_ACC(7)
  }
  for (; e + 3 < re; e += 4) {
    EDGE_LOAD(0, e) EDGE_LOAD(1, e + 1) EDGE_LOAD(2, e + 2)
    EDGE_LOAD(3, e + 3)
    EDGE_ACC(0) EDGE_ACC(1) EDGE_ACC(2) EDGE_ACC(3)
  }
  for (; e < re; ++e) {
    EDGE_LOAD(0, e)
    EDGE_ACC(0)
  }
  float inv = 1.f / ssum;
  float2 r = unpack_bf16(*(const unsigned*)&res[(size_t)n * HF + c2]);
  float2 bi = *(const float2*)&bias[c2];
  float vx = fmaf(ax, inv, r.x + bi.x);
  float vy = fmaf(ay, inv, r.y + bi.y);
  vx = (vx > 0.f) ? vx : expm1f(vx);
  vy = (vy > 0.f) ? vy : expm1f(vy);
  *(unsigned*)&H[(size_t)n * HF + c2] = pack_bf16(vx, vy);
}

// Layer 2 epilogue: head-mean -> sigmoid gate -> readout atomics.
__global__ __launch_bounds__(256) void agg2_fused(
    const int* __restrict__ row_ptr, const int* __restrict__ ssorted,
    const float* __restrict__ el, const float* __restrict__ er,
    const bf16* __restrict__ feat, const bf16* __restrict__ h1,
    const float* __restrict__ bias, const float* __restrict__ ww,
    const float* __restrict__ wb, const int* __restrict__ gids,
    float* __restrict__ hsum, unsigned* __restrict__ hmax, int N) {
  int n = blockIdx.x * 4 + (threadIdx.x >> 6);
  if (n >= N) return;
  const int lane = threadIdx.x & 63;
  const int c2 = lane * 2, h = lane >> 4;
  const int rb = row_ptr[n], re = row_ptr[n + 1];
  const float ern = er[n * HEADS + h];

  float ax = 0.f, ay = 0.f, ssum = 0.f;
  int e = rb;
  for (; e + 7 < re; e += 8) {
    EDGE_LOAD(0, e) EDGE_LOAD(1, e + 1) EDGE_LOAD(2, e + 2)
    EDGE_LOAD(3, e + 3) EDGE_LOAD(4, e + 4) EDGE_LOAD(5, e + 5)
    EDGE_LOAD(6, e + 6) EDGE_LOAD(7, e + 7)
    EDGE_ACC(0) EDGE_ACC(1) EDGE_ACC(2) EDGE_ACC(3)
    EDGE_ACC(4) EDGE_ACC(5) EDGE_ACC(6) EDGE_ACC(7)
  }
  for (; e + 3 < re; e += 4) {
    EDGE_LOAD(0, e) EDGE_LOAD(1, e + 1) EDGE_LOAD(2, e + 2)
    EDGE_LOAD(3, e + 3)
    EDGE_ACC(0) EDGE_ACC(1) EDGE_ACC(2) EDGE_ACC(3)
  }
  for (; e < re; ++e) {
    EDGE_LOAD(0, e)
    EDGE_ACC(0)
  }
  float inv = 1.f / ssum;
  float2 r = unpack_bf16(*(const unsigned*)&h1[(size_t)n * HF + c2]);
  float2 bi = *(const float2*)&bias[c2];
  ax = fmaf(ax, inv, r.x + bi.x);
  ay = fmaf(ay, inv, r.y + bi.y);
  // head mean: after xor 16,32 every lane holds the sum over its 4-head class
#pragma unroll
  for (int off = 16; off < 64; off <<= 1) {
    ax += __shfl_xor(ax, off);
    ay += __shfl_xor(ay, off);
  }
  ax *= 0.25f;
  ay *= 0.25f;
  // sigmoid gate: dot(node_feats, ww) reduced over the 16-lane col groups
  int c = c2 & 31;
  float d = fmaf(ax, ww[c], ay * ww[c + 1]);
#pragma unroll
  for (int off = 1; off < 16; off <<= 1) d += __shfl_xor(d, off);
  float wv = 1.f / (1.f + __expf(-(d + wb[0])));
  if (lane < 16) {
    int g = gids[n];
    atomicAdd(&hsum[g * OUTF + c], wv * ax);
    atomicAdd(&hsum[g * OUTF + c + 1], wv * ay);
    atomicMax(&hmax[g * OUTF + c], enc_f(ax));
    atomicMax(&hmax[g * OUTF + c + 1], enc_f(ay));
  }
}

// ============================ readout tail =================================
__global__ __launch_bounds__(256) void init_readout_kernel(
    float* __restrict__ hsum, unsigned* __restrict__ hmax, int g32) {
  int t = blockIdx.x * 256 + threadIdx.x;
  if (t >= g32) return;
  hsum[t] = 0.f;
  hmax[t] = NEG_INF_ENC;
}

__global__ __launch_bounds__(256) void final_gemm_kernel(
    const float* __restrict__ hsum, const unsigned* __restrict__ hmax,
    const float* __restrict__ tw, const float* __restrict__ tb,
    float* __restrict__ out, int G) {
  __shared__ float tws[64 * PRED_DIM];
  for (int i = threadIdx.x; i < 64 * PRED_DIM; i += 256) tws[i] = tw[i];
  __syncthreads();
  int g = blockIdx.x * 2 + (threadIdx.x >> 7);
  int p = threadIdx.x & 127;
  if (g >= G) return;
  float acc = tb[p];
#pragma unroll
  for (int k = 0; k < OUTF; ++k)
    acc = fmaf(hsum[g * OUTF + k], tws[k * PRED_DIM + p], acc);
#pragma unroll
  for (int k = 0; k < OUTF; ++k)
    acc = fmaf(dec_f(hmax[g * OUTF + k]), tws[(OUTF + k) * PRED_DIM + p], acc);
  out[(size_t)g * PRED_DIM + p] = acc;
}

static inline int cdiv(long long a, int b) { return (int)((a + b - 1) / b); }

extern "C" void kernel_launch(void* const* d_in, const int* in_sizes, int n_in,
                              void* d_out, int out_size, void* d_ws,
                              size_t ws_size, hipStream_t stream) {
  const float* feats   = (const float*)d_in[0];
  const int*   src     = (const int*)d_in[1];
  const int*   dst     = (const int*)d_in[2];
  const int*   gids    = (const int*)d_in[3];
  const float* fc1_w   = (const float*)d_in[4];
  const float* attn_l1 = (const float*)d_in[5];
  const float* attn_r1 = (const float*)d_in[6];
  const float* res1_w  = (const float*)d_in[7];
  const float* bias1   = (const float*)d_in[8];
  const float* fc2_w   = (const float*)d_in[9];
  const float* attn_l2 = (const float*)d_in[10];
  const float* attn_r2 = (const float*)d_in[11];
  const float* bias2   = (const float*)d_in[12];
  const float* ww      = (const float*)d_in[13];
  const float* wb      = (const float*)d_in[14];
  const float* tw      = (const float*)d_in[15];
  const float* tb      = (const float*)d_in[16];
  float* out = (float*)d_out;

  const int N = in_sizes[0] / IN_FEATS;  // 100000
  const int E = in_sizes[1];             // 900000
  const int G = out_size / PRED_DIM;     // 2048
  const int NB = cdiv(N, 2048);

  // ---- workspace layout ----
  bf16* A = (bf16*)d_ws;                      // N*128 bf16 (feat1/feat2)
  bf16* B = A + (size_t)N * HF;               // N*128 bf16 (res1)
  bf16* H = B + (size_t)N * HF;               // N*128 bf16 (h1)
  float* el = (float*)(H + (size_t)N * HF);   // N*4
  float* er = el + (size_t)N * HEADS;         // N*4
  float* hsum = er + (size_t)N * HEADS;       // G*32
  unsigned* hmax = (unsigned*)(hsum + (size_t)G * OUTF);  // G*32
  int* deg     = (int*)(hmax + (size_t)G * OUTF);  // N
  int* cursor  = deg + N;                          // N
  int* row_ptr = cursor + N;                       // N+1
  int* ssorted = row_ptr + (N + 1);                // E
  int* bsum    = ssorted + E;                      // NB
  int* bpre    = bsum + NB;                        // NB

  const int gblk = cdiv(N, 64);
  const int nwblk = cdiv(N, 4);

  // ===================== CSR build =====================
  hipMemsetAsync(deg, 0, (size_t)N * sizeof(int), stream);
  hipMemsetAsync(cursor, 0, (size_t)N * sizeof(int), stream);
  hist_kernel<<<cdiv(E, 256), 256, 0, stream>>>(dst, deg, E);
  scan1_kernel<<<NB, 256, 0, stream>>>(deg, row_ptr, bsum, N);
  scan2_kernel<<<1, 64, 0, stream>>>(bsum, bpre, NB);
  scan3_kernel<<<cdiv(N, 256), 256, 0, stream>>>(row_ptr, bpre, N, E);
  scatter_kernel<<<cdiv(E, 256), 256, 0, stream>>>(src, dst, row_ptr, cursor,
                                                   ssorted, E);

  // ===================== Layer 1 =====================
  gemm_dual<IN_FEATS><<<gblk, 256, 0, stream>>>(
      feats, fc1_w, res1_w, attn_l1, attn_r1, A, B, el, er, N);
  agg1_fused<<<nwblk, 256, 0, stream>>>(row_ptr, ssorted, el, er, A, B, H,
                                        bias1, N);

  // ===================== Layer 2 =====================
  gemm_tiled<HF, bf16, true><<<gblk, 256, 0, stream>>>(
      H, fc2_w, attn_l2, attn_r2, A, el, er, N);
  init_readout_kernel<<<cdiv(G * OUTF, 256), 256, 0, stream>>>(hsum, hmax,
                                                               G * OUTF);
  agg2_fused<<<nwblk, 256, 0, stream>>>(row_ptr, ssorted, el, er, A, H, bias2,
                                        ww, wb, gids, hsum, hmax, N);

  // ===================== Readout =====================
  final_gemm_kernel<<<cdiv(G, 2), 256, 0, stream>>>(hsum, hmax, tw, tb, out, G);
}

// Round 13
// 402.562 us; speedup vs baseline: 1.2155x; 1.1512x over previous
//
#include <hip/hip_runtime.h>
#include <hip/hip_bf16.h>

// ---------------------------------------------------------------------------
// DGL GAT (2-layer, heads=4, out=32) + WeightedSumAndMax readout.
// Round 12: node GEMMs ported to MFMA (v_mfma_f32_16x16x32_bf16). Block =
//           64 nodes x 128 cols, 4 waves, 8 col-tiles/wave. X and W^T staged
//           in LDS as bf16 pairs with 40-elem row pad (2-way banks = free).
//           Scores epilogue from MFMA accumulators. Agg/CSR/readout frozen
//           at round-12 state (r8 agg form).
// ---------------------------------------------------------------------------

#define HEADS 4
#define OUTF 32
#define HF 128            // HEADS*OUTF
#define IN_FEATS 74
#define PRED_DIM 128
#define NEG_SLOPE 0.2f
#define NEG_INF_ENC 0x007fffffu   // enc_f(-inf)

typedef __hip_bfloat16 bf16;
typedef __hip_bfloat162 bf16x2;
typedef __attribute__((ext_vector_type(8))) short bf16x8v;  // 8 bf16, 4 VGPRs
typedef __attribute__((ext_vector_type(4))) float f32x4v;   // MFMA C/D

__device__ __forceinline__ unsigned enc_f(float f) {
  unsigned u = __float_as_uint(f);
  return (u & 0x80000000u) ? ~u : (u | 0x80000000u);
}
__device__ __forceinline__ float dec_f(unsigned k) {
  return (k & 0x80000000u) ? __uint_as_float(k & 0x7fffffffu)
                           : __uint_as_float(~k);
}
__device__ __forceinline__ unsigned pack_bf16(float a, float b) {
  bf16x2 h = __float22bfloat162_rn(make_float2(a, b));
  return *(unsigned*)&h;
}
__device__ __forceinline__ float2 unpack_bf16(unsigned u) {
  bf16x2 h = *(bf16x2*)&u;
  return __bfloat1622float2(h);
}
__device__ __forceinline__ float lrelu(float v) {
  return fmaxf(v, NEG_SLOPE * v);
}

// ===================== MFMA node GEMM building blocks ======================
// LDS layouts (unsigned = 2 bf16). Row pad to 20 uints (40 bf16, 80B):
// bank stride 20 -> at most 2-way aliasing (free).
//   Xl[64][20]   : X tile, [node][k-pair]
//   Wt[128][20]  : W tile TRANSPOSED, [col][k-pair]

// Stage X tile (64 nodes x 32 k) as bf16 pairs. XT = float or bf16.
template <typename XT, int K>
__device__ __forceinline__ void stage_X(const XT* __restrict__ X,
                                        unsigned* Xl, int n0, int k0, int N,
                                        int tid) {
  int n = tid >> 2;            // 0..63
  int kp0 = (tid & 3) * 4;     // 0,4,8,12
  int gn = n0 + n;
  uint4 val = make_uint4(0u, 0u, 0u, 0u);
  if (gn < N) {
    if (sizeof(XT) == 4) {  // f32 input
      const float* Xf = (const float*)X;
      unsigned v[4];
#pragma unroll
      for (int j = 0; j < 4; ++j) {
        int k = k0 + (kp0 + j) * 2;
        float2 xv = make_float2(0.f, 0.f);
        if (k < K) xv = *(const float2*)&Xf[(size_t)gn * K + k];  // K even
        v[j] = pack_bf16(xv.x, xv.y);
      }
      val = make_uint4(v[0], v[1], v[2], v[3]);
    } else {  // bf16 input (K multiple of 32 -> always in range)
      const unsigned* Xu = (const unsigned*)X;
      val = *(const uint4*)&Xu[((size_t)gn * K + k0) / 2 + kp0];
    }
  }
  *(uint4*)&Xl[n * 20 + kp0] = val;
}

// Stage W tile (32 k x 128 cols) transposed into Wt[col][k-pair].
template <int K>
__device__ __forceinline__ void stage_W(const float* __restrict__ W,
                                        unsigned* Wt, int k0, int tid) {
#pragma unroll
  for (int i = 0; i < 8; ++i) {
    int c = tid & 127;
    int kp = i * 2 + (tid >> 7);
    int k = k0 + kp * 2;
    float a = 0.f, b = 0.f;
    if (k < K) {  // K even -> k+1 < K too
      a = W[(size_t)k * HF + c];
      b = W[(size_t)(k + 1) * HF + c];
    }
    Wt[c * 20 + kp] = pack_bf16(a, b);
  }
}

// Scores epilogue from accumulators (col = lane&15, row = q*4+reg).
__device__ __forceinline__ void scores_epilogue(
    const f32x4v* acc, const float* __restrict__ attn_l,
    const float* __restrict__ attn_r, float* __restrict__ el,
    float* __restrict__ er, int n0, int w, int q, int cc, int N) {
#pragma unroll
  for (int r = 0; r < 4; ++r) {
    int n = n0 + w * 16 + q * 4 + r;
    float pls[4], prs[4];
#pragma unroll
    for (int h = 0; h < 4; ++h) {
      float pl = acc[2 * h][r] * attn_l[h * 32 + cc] +
                 acc[2 * h + 1][r] * attn_l[h * 32 + 16 + cc];
      float pr = acc[2 * h][r] * attn_r[h * 32 + cc] +
                 acc[2 * h + 1][r] * attn_r[h * 32 + 16 + cc];
#pragma unroll
      for (int off = 1; off < 16; off <<= 1) {
        pl += __shfl_xor(pl, off);
        pr += __shfl_xor(pr, off);
      }
      pls[h] = pl;
      prs[h] = pr;
    }
    if (cc == 0 && n < N) {
#pragma unroll
      for (int h = 0; h < 4; ++h) {
        el[n * HEADS + h] = pls[h];
        er[n * HEADS + h] = prs[h];
      }
    }
  }
}

// Single-matrix MFMA GEMM + scores (layer 2). out bf16.
template <int K, typename XT>
__global__ __launch_bounds__(256) void mfma_gemm(
    const XT* __restrict__ X, const float* __restrict__ W,
    const float* __restrict__ attn_l, const float* __restrict__ attn_r,
    bf16* __restrict__ out, float* __restrict__ el, float* __restrict__ er,
    int N) {
  __shared__ __align__(16) unsigned Xl[64 * 20];
  __shared__ __align__(16) unsigned Wt[128 * 20];
  const int tid = threadIdx.x;
  const int w = tid >> 6;
  const int lane = tid & 63;
  const int cc = lane & 15;
  const int q = lane >> 4;
  const int n0 = blockIdx.x * 64;

  f32x4v acc[8];
#pragma unroll
  for (int t = 0; t < 8; ++t) acc[t] = f32x4v{0.f, 0.f, 0.f, 0.f};

  constexpr int KSTEPS = (K + 31) / 32;
  for (int ks = 0; ks < KSTEPS; ++ks) {
    int k0 = ks * 32;
    stage_X<XT, K>(X, Xl, n0, k0, N, tid);
    stage_W<K>(W, Wt, k0, tid);
    __syncthreads();
    bf16x8v a = *(const bf16x8v*)&Xl[(w * 16 + cc) * 20 + q * 4];
#pragma unroll
    for (int t = 0; t < 8; ++t) {
      bf16x8v b = *(const bf16x8v*)&Wt[(t * 16 + cc) * 20 + q * 4];
      acc[t] = __builtin_amdgcn_mfma_f32_16x16x32_bf16(a, b, acc[t], 0, 0, 0);
    }
    __syncthreads();
  }
#pragma unroll
  for (int r = 0; r < 4; ++r) {
    int n = n0 + w * 16 + q * 4 + r;
    if (n < N) {
#pragma unroll
      for (int t = 0; t < 8; ++t)
        out[(size_t)n * HF + t * 16 + cc] = __float2bfloat16(acc[t][r]);
    }
  }
  scores_epilogue(acc, attn_l, attn_r, el, er, n0, w, q, cc, N);
}

// Dual-matrix MFMA GEMM (layer 1): W1=fc1 -> outA + scores, W2=res1 -> outB.
template <int K>
__global__ __launch_bounds__(256) void mfma_dual(
    const float* __restrict__ X, const float* __restrict__ W1,
    const float* __restrict__ W2, const float* __restrict__ attn_l,
    const float* __restrict__ attn_r, bf16* __restrict__ outA,
    bf16* __restrict__ outB, float* __restrict__ el, float* __restrict__ er,
    int N) {
  __shared__ __align__(16) unsigned Xl[64 * 20];
  __shared__ __align__(16) unsigned Wt1[128 * 20];
  __shared__ __align__(16) unsigned Wt2[128 * 20];
  const int tid = threadIdx.x;
  const int w = tid >> 6;
  const int lane = tid & 63;
  const int cc = lane & 15;
  const int q = lane >> 4;
  const int n0 = blockIdx.x * 64;

  f32x4v acc1[8], acc2[8];
#pragma unroll
  for (int t = 0; t < 8; ++t) {
    acc1[t] = f32x4v{0.f, 0.f, 0.f, 0.f};
    acc2[t] = f32x4v{0.f, 0.f, 0.f, 0.f};
  }

  constexpr int KSTEPS = (K + 31) / 32;
  for (int ks = 0; ks < KSTEPS; ++ks) {
    int k0 = ks * 32;
    stage_X<float, K>(X, Xl, n0, k0, N, tid);
    stage_W<K>(W1, Wt1, k0, tid);
    stage_W<K>(W2, Wt2, k0, tid);
    __syncthreads();
    bf16x8v a = *(const bf16x8v*)&Xl[(w * 16 + cc) * 20 + q * 4];
#pragma unroll
    for (int t = 0; t < 8; ++t) {
      bf16x8v b1 = *(const bf16x8v*)&Wt1[(t * 16 + cc) * 20 + q * 4];
      bf16x8v b2 = *(const bf16x8v*)&Wt2[(t * 16 + cc) * 20 + q * 4];
      acc1[t] = __builtin_amdgcn_mfma_f32_16x16x32_bf16(a, b1, acc1[t], 0, 0, 0);
      acc2[t] = __builtin_amdgcn_mfma_f32_16x16x32_bf16(a, b2, acc2[t], 0, 0, 0);
    }
    __syncthreads();
  }
#pragma unroll
  for (int r = 0; r < 4; ++r) {
    int n = n0 + w * 16 + q * 4 + r;
    if (n < N) {
#pragma unroll
      for (int t = 0; t < 8; ++t) {
        outA[(size_t)n * HF + t * 16 + cc] = __float2bfloat16(acc1[t][r]);
        outB[(size_t)n * HF + t * 16 + cc] = __float2bfloat16(acc2[t][r]);
      }
    }
  }
  scores_epilogue(acc1, attn_l, attn_r, el, er, n0, w, q, cc, N);
}

// ============================ CSR build ====================================
__global__ __launch_bounds__(256) void hist_kernel(
    const int* __restrict__ dst, int* __restrict__ deg, int E) {
  int e = blockIdx.x * 256 + threadIdx.x;
  if (e < E) atomicAdd(&deg[dst[e]], 1);
}

__global__ __launch_bounds__(256) void scan1_kernel(
    const int* __restrict__ deg, int* __restrict__ row_ptr,
    int* __restrict__ bsum, int N) {
  const int base = blockIdx.x * 2048;
  const int tbase = base + threadIdx.x * 8;
  int vals[8];
  int tsum = 0;
#pragma unroll
  for (int i = 0; i < 8; ++i) {
    int idx = tbase + i;
    vals[i] = (idx < N) ? deg[idx] : 0;
    tsum += vals[i];
  }
  const int lane = threadIdx.x & 63, wv = threadIdx.x >> 6;
  int incl = tsum;
#pragma unroll
  for (int off = 1; off < 64; off <<= 1) {
    int nv = __shfl_up(incl, off);
    if (lane >= off) incl += nv;
  }
  __shared__ int wsum[4];
  if (lane == 63) wsum[wv] = incl;
  __syncthreads();
  int woff = 0;
  for (int w = 0; w < wv; ++w) woff += wsum[w];
  int run = woff + incl - tsum;
#pragma unroll
  for (int i = 0; i < 8; ++i) {
    int idx = tbase + i;
    if (idx < N) row_ptr[idx] = run;
    run += vals[i];
  }
  if (threadIdx.x == 255) bsum[blockIdx.x] = woff + incl;
}

__global__ __launch_bounds__(64) void scan2_kernel(
    const int* __restrict__ bsum, int* __restrict__ bpre, int NB) {
  const int lane = threadIdx.x;
  int running = 0;
  for (int c = 0; c < NB; c += 64) {
    int v = (c + lane < NB) ? bsum[c + lane] : 0;
    int incl = v;
#pragma unroll
    for (int off = 1; off < 64; off <<= 1) {
      int nv = __shfl_up(incl, off);
      if (lane >= off) incl += nv;
    }
    if (c + lane < NB) bpre[c + lane] = running + incl - v;
    running += __shfl(incl, 63);
  }
}

__global__ __launch_bounds__(256) void scan3_kernel(
    int* __restrict__ row_ptr, const int* __restrict__ bpre, int N, int E) {
  int t = blockIdx.x * 256 + threadIdx.x;
  if (t < N) row_ptr[t] += bpre[t >> 11];
  if (t == 0) row_ptr[N] = E;
}

__global__ __launch_bounds__(256) void scatter_kernel(
    const int* __restrict__ src, const int* __restrict__ dst,
    const int* __restrict__ row_ptr, int* __restrict__ cursor,
    int* __restrict__ ssorted, int E) {
  int e = blockIdx.x * 256 + threadIdx.x;
  if (e >= E) return;
  int d = dst[e];
  int pos = row_ptr[d] + atomicAdd(&cursor[d], 1);
  ssorted[pos] = src[e];
}

// ============ fused softmax + aggregate (single edge pass) =================
// [round-8 form — best known] One wave per node; lane = cols (2l,2l+1),
// head h = lane>>4. 8-edge straight-line unroll.

#define EDGE_LOAD(i, e_)                                                    \
  int s##i = ssorted[e_];                                                   \
  float x##i; float2 f##i;                                                  \
  {                                                                         \
    float v = el[s##i * HEADS + h] + ern;                                   \
    x##i = __expf(lrelu(v));                                                \
    f##i = unpack_bf16(*(const unsigned*)&feat[(size_t)s##i * HF + c2]);    \
  }
#define EDGE_ACC(i)                                                         \
  ssum += x##i;                                                             \
  ax = fmaf(x##i, f##i.x, ax);                                              \
  ay = fmaf(x##i, f##i.y, ay);

// Layer 1 epilogue: H[n] = elu(inv*agg + res[n] + bias)   (res, H bf16)
__global__ __launch_bounds__(256) void agg1_fused(
    const int* __restrict__ row_ptr, const int* __restrict__ ssorted,
    const float* __restrict__ el, const float* __restrict__ er,
    const bf16* __restrict__ feat, const bf16* __restrict__ res,
    bf16* __restrict__ H, const float* __restrict__ bias, int N) {
  int n = blockIdx.x * 4 + (threadIdx.x >> 6);
  if (n >= N) return;
  const int lane = threadIdx.x & 63;
  const int c2 = lane * 2, h = lane >> 4;
  const int rb = row_ptr[n], re = row_ptr[n + 1];
  const float ern = er[n * HEADS + h];

  float ax = 0.f, ay = 0.f, ssum = 0.f;
  int e = rb;
  for (; e + 7 < re; e += 8) {
    EDGE_LOAD(0, e) EDGE_LOAD(1, e + 1) EDGE_LOAD(2, e + 2)
    EDGE_LOAD(3, e + 3) EDGE_LOAD(4, e + 4) EDGE_LOAD(5, e + 5)
    EDGE_LOAD(6, e + 6) EDGE_LOAD(7, e + 7)
    EDGE_ACC(0) EDGE_ACC(1) EDGE_ACC(2) EDGE_ACC(3)
    EDGE_ACC(4) EDGE_ACC(5) EDGE_ACC(6) EDGE_ACC(7)
  }
  for (; e + 3 < re; e += 4) {
    EDGE_LOAD(0, e) EDGE_LOAD(1, e + 1) EDGE_LOAD(2, e + 2)
    EDGE_LOAD(3, e + 3)
    EDGE_ACC(0) EDGE_ACC(1) EDGE_ACC(2) EDGE_ACC(3)
  }
  for (; e < re; ++e) {
    EDGE_LOAD(0, e)
    EDGE_ACC(0)
  }
  float inv = 1.f / ssum;
  float2 r = unpack_bf16(*(const unsigned*)&res[(size_t)n * HF + c2]);
  float2 bi = *(const float2*)&bias[c2];
  float vx = fmaf(ax, inv, r.x + bi.x);
  float vy = fmaf(ay, inv, r.y + bi.y);
  vx = (vx > 0.f) ? vx : expm1f(vx);
  vy = (vy > 0.f) ? vy : expm1f(vy);
  *(unsigned*)&H[(size_t)n * HF + c2] = pack_bf16(vx, vy);
}

// Layer 2 epilogue: head-mean -> sigmoid gate -> readout atomics.
__global__ __launch_bounds__(256) void agg2_fused(
    const int* __restrict__ row_ptr, const int* __restrict__ ssorted,
    const float* __restrict__ el, const float* __restrict__ er,
    const bf16* __restrict__ feat, const bf16* __restrict__ h1,
    const float* __restrict__ bias, const float* __restrict__ ww,
    const float* __restrict__ wb, const int* __restrict__ gids,
    float* __restrict__ hsum, unsigned* __restrict__ hmax, int N) {
  int n = blockIdx.x * 4 + (threadIdx.x >> 6);
  if (n >= N) return;
  const int lane = threadIdx.x & 63;
  const int c2 = lane * 2, h = lane >> 4;
  const int rb = row_ptr[n], re = row_ptr[n + 1];
  const float ern = er[n * HEADS + h];

  float ax = 0.f, ay = 0.f, ssum = 0.f;
  int e = rb;
  for (; e + 7 < re; e += 8) {
    EDGE_LOAD(0, e) EDGE_LOAD(1, e + 1) EDGE_LOAD(2, e + 2)
    EDGE_LOAD(3, e + 3) EDGE_LOAD(4, e + 4) EDGE_LOAD(5, e + 5)
    EDGE_LOAD(6, e + 6) EDGE_LOAD(7, e + 7)
    EDGE_ACC(0) EDGE_ACC(1) EDGE_ACC(2) EDGE_ACC(3)
    EDGE_ACC(4) EDGE_ACC(5) EDGE_ACC(6) EDGE_ACC(7)
  }
  for (; e + 3 < re; e += 4) {
    EDGE_LOAD(0, e) EDGE_LOAD(1, e + 1) EDGE_LOAD(2, e + 2)
    EDGE_LOAD(3, e + 3)
    EDGE_ACC(0) EDGE_ACC(1) EDGE_ACC(2) EDGE_ACC(3)
  }
  for (; e < re; ++e) {
    EDGE_LOAD(0, e)
    EDGE_ACC(0)
  }
  float inv = 1.f / ssum;
  float2 r = unpack_bf16(*(const unsigned*)&h1[(size_t)n * HF + c2]);
  float2 bi = *(const float2*)&bias[c2];
  ax = fmaf(ax, inv, r.x + bi.x);
  ay = fmaf(ay, inv, r.y + bi.y);
#pragma unroll
  for (int off = 16; off < 64; off <<= 1) {
    ax += __shfl_xor(ax, off);
    ay += __shfl_xor(ay, off);
  }
  ax *= 0.25f;
  ay *= 0.25f;
  int c = c2 & 31;
  float d = fmaf(ax, ww[c], ay * ww[c + 1]);
#pragma unroll
  for (int off = 1; off < 16; off <<= 1) d += __shfl_xor(d, off);
  float wv = 1.f / (1.f + __expf(-(d + wb[0])));
  if (lane < 16) {
    int g = gids[n];
    atomicAdd(&hsum[g * OUTF + c], wv * ax);
    atomicAdd(&hsum[g * OUTF + c + 1], wv * ay);
    atomicMax(&hmax[g * OUTF + c], enc_f(ax));
    atomicMax(&hmax[g * OUTF + c + 1], enc_f(ay));
  }
}

// ============================ readout tail =================================
__global__ __launch_bounds__(256) void init_readout_kernel(
    float* __restrict__ hsum, unsigned* __restrict__ hmax, int g32) {
  int t = blockIdx.x * 256 + threadIdx.x;
  if (t >= g32) return;
  hsum[t] = 0.f;
  hmax[t] = NEG_INF_ENC;
}

__global__ __launch_bounds__(256) void final_gemm_kernel(
    const float* __restrict__ hsum, const unsigned* __restrict__ hmax,
    const float* __restrict__ tw, const float* __restrict__ tb,
    float* __restrict__ out, int G) {
  __shared__ float tws[64 * PRED_DIM];
  for (int i = threadIdx.x; i < 64 * PRED_DIM; i += 256) tws[i] = tw[i];
  __syncthreads();
  int g = blockIdx.x * 2 + (threadIdx.x >> 7);
  int p = threadIdx.x & 127;
  if (g >= G) return;
  float acc = tb[p];
#pragma unroll
  for (int k = 0; k < OUTF; ++k)
    acc = fmaf(hsum[g * OUTF + k], tws[k * PRED_DIM + p], acc);
#pragma unroll
  for (int k = 0; k < OUTF; ++k)
    acc = fmaf(dec_f(hmax[g * OUTF + k]), tws[(OUTF + k) * PRED_DIM + p], acc);
  out[(size_t)g * PRED_DIM + p] = acc;
}

static inline int cdiv(long long a, int b) { return (int)((a + b - 1) / b); }

extern "C" void kernel_launch(void* const* d_in, const int* in_sizes, int n_in,
                              void* d_out, int out_size, void* d_ws,
                              size_t ws_size, hipStream_t stream) {
  const float* feats   = (const float*)d_in[0];
  const int*   src     = (const int*)d_in[1];
  const int*   dst     = (const int*)d_in[2];
  const int*   gids    = (const int*)d_in[3];
  const float* fc1_w   = (const float*)d_in[4];
  const float* attn_l1 = (const float*)d_in[5];
  const float* attn_r1 = (const float*)d_in[6];
  const float* res1_w  = (const float*)d_in[7];
  const float* bias1   = (const float*)d_in[8];
  const float* fc2_w   = (const float*)d_in[9];
  const float* attn_l2 = (const float*)d_in[10];
  const float* attn_r2 = (const float*)d_in[11];
  const float* bias2   = (const float*)d_in[12];
  const float* ww      = (const float*)d_in[13];
  const float* wb      = (const float*)d_in[14];
  const float* tw      = (const float*)d_in[15];
  const float* tb      = (const float*)d_in[16];
  float* out = (float*)d_out;

  const int N = in_sizes[0] / IN_FEATS;  // 100000
  const int E = in_sizes[1];             // 900000
  const int G = out_size / PRED_DIM;     // 2048
  const int NB = cdiv(N, 2048);

  // ---- workspace layout ----
  bf16* A = (bf16*)d_ws;                      // N*128 bf16 (feat1/feat2)
  bf16* B = A + (size_t)N * HF;               // N*128 bf16 (res1)
  bf16* H = B + (size_t)N * HF;               // N*128 bf16 (h1)
  float* el = (float*)(H + (size_t)N * HF);   // N*4
  float* er = el + (size_t)N * HEADS;         // N*4
  float* hsum = er + (size_t)N * HEADS;       // G*32
  unsigned* hmax = (unsigned*)(hsum + (size_t)G * OUTF);  // G*32
  int* deg     = (int*)(hmax + (size_t)G * OUTF);  // N
  int* cursor  = deg + N;                          // N
  int* row_ptr = cursor + N;                       // N+1
  int* ssorted = row_ptr + (N + 1);                // E
  int* bsum    = ssorted + E;                      // NB
  int* bpre    = bsum + NB;                        // NB

  const int gblk = cdiv(N, 64);
  const int nwblk = cdiv(N, 4);

  // ===================== CSR build =====================
  hipMemsetAsync(deg, 0, (size_t)N * sizeof(int), stream);
  hipMemsetAsync(cursor, 0, (size_t)N * sizeof(int), stream);
  hist_kernel<<<cdiv(E, 256), 256, 0, stream>>>(dst, deg, E);
  scan1_kernel<<<NB, 256, 0, stream>>>(deg, row_ptr, bsum, N);
  scan2_kernel<<<1, 64, 0, stream>>>(bsum, bpre, NB);
  scan3_kernel<<<cdiv(N, 256), 256, 0, stream>>>(row_ptr, bpre, N, E);
  scatter_kernel<<<cdiv(E, 256), 256, 0, stream>>>(src, dst, row_ptr, cursor,
                                                   ssorted, E);

  // ===================== Layer 1 =====================
  mfma_dual<IN_FEATS><<<gblk, 256, 0, stream>>>(
      feats, fc1_w, res1_w, attn_l1, attn_r1, A, B, el, er, N);
  agg1_fused<<<nwblk, 256, 0, stream>>>(row_ptr, ssorted, el, er, A, B, H,
                                        bias1, N);

  // ===================== Layer 2 =====================
  mfma_gemm<HF, bf16><<<gblk, 256, 0, stream>>>(
      H, fc2_w, attn_l2, attn_r2, A, el, er, N);
  init_readout_kernel<<<cdiv(G * OUTF, 256), 256, 0, stream>>>(hsum, hmax,
                                                               G * OUTF);
  agg2_fused<<<nwblk, 256, 0, stream>>>(row_ptr, ssorted, el, er, A, H, bias2,
                                        ww, wb, gids, hsum, hmax, N);

  // ===================== Readout =====================
  final_gemm_kernel<<<cdiv(G, 2), 256, 0, stream>>>(hsum, hmax, tw, tb, out, G);
}

// Round 14
// 388.915 us; speedup vs baseline: 1.2582x; 1.0351x over previous
//
#include <hip/hip_runtime.h>
#include <hip/hip_bf16.h>

// ---------------------------------------------------------------------------
// DGL GAT (2-layer, heads=4, out=32) + WeightedSumAndMax readout.
// Round 13: agg loop micro-surgery — (1) 8 ssorted broadcast-loads replaced
//           by ONE 32B vector load + __shfl lane broadcasts (24->17 VMEM
//           issues/burst); (2) tail = single predicated 8-burst with clamped
//           indices (1 serial latency round instead of up to 4). Plus:
//           deg/cursor memsets merged, init_readout folded into hist.
//           MFMA GEMMs and everything else frozen at round-12 state.
// ---------------------------------------------------------------------------

#define HEADS 4
#define OUTF 32
#define HF 128            // HEADS*OUTF
#define IN_FEATS 74
#define PRED_DIM 128
#define NEG_SLOPE 0.2f
#define NEG_INF_ENC 0x007fffffu   // enc_f(-inf)

typedef __hip_bfloat16 bf16;
typedef __hip_bfloat162 bf16x2;
typedef __attribute__((ext_vector_type(8))) short bf16x8v;  // 8 bf16, 4 VGPRs
typedef __attribute__((ext_vector_type(4))) float f32x4v;   // MFMA C/D

__device__ __forceinline__ unsigned enc_f(float f) {
  unsigned u = __float_as_uint(f);
  return (u & 0x80000000u) ? ~u : (u | 0x80000000u);
}
__device__ __forceinline__ float dec_f(unsigned k) {
  return (k & 0x80000000u) ? __uint_as_float(k & 0x7fffffffu)
                           : __uint_as_float(~k);
}
__device__ __forceinline__ unsigned pack_bf16(float a, float b) {
  bf16x2 h = __float22bfloat162_rn(make_float2(a, b));
  return *(unsigned*)&h;
}
__device__ __forceinline__ float2 unpack_bf16(unsigned u) {
  bf16x2 h = *(bf16x2*)&u;
  return __bfloat1622float2(h);
}
__device__ __forceinline__ float lrelu(float v) {
  return fmaxf(v, NEG_SLOPE * v);
}

// ===================== MFMA node GEMM building blocks ======================
// LDS layouts (unsigned = 2 bf16). Row pad to 20 uints (40 bf16, 80B):
// bank stride 20 -> at most 2-way aliasing (free).

template <typename XT, int K>
__device__ __forceinline__ void stage_X(const XT* __restrict__ X,
                                        unsigned* Xl, int n0, int k0, int N,
                                        int tid) {
  int n = tid >> 2;            // 0..63
  int kp0 = (tid & 3) * 4;     // 0,4,8,12
  int gn = n0 + n;
  uint4 val = make_uint4(0u, 0u, 0u, 0u);
  if (gn < N) {
    if (sizeof(XT) == 4) {  // f32 input
      const float* Xf = (const float*)X;
      unsigned v[4];
#pragma unroll
      for (int j = 0; j < 4; ++j) {
        int k = k0 + (kp0 + j) * 2;
        float2 xv = make_float2(0.f, 0.f);
        if (k < K) xv = *(const float2*)&Xf[(size_t)gn * K + k];  // K even
        v[j] = pack_bf16(xv.x, xv.y);
      }
      val = make_uint4(v[0], v[1], v[2], v[3]);
    } else {  // bf16 input (K multiple of 32)
      const unsigned* Xu = (const unsigned*)X;
      val = *(const uint4*)&Xu[((size_t)gn * K + k0) / 2 + kp0];
    }
  }
  *(uint4*)&Xl[n * 20 + kp0] = val;
}

template <int K>
__device__ __forceinline__ void stage_W(const float* __restrict__ W,
                                        unsigned* Wt, int k0, int tid) {
#pragma unroll
  for (int i = 0; i < 8; ++i) {
    int c = tid & 127;
    int kp = i * 2 + (tid >> 7);
    int k = k0 + kp * 2;
    float a = 0.f, b = 0.f;
    if (k < K) {
      a = W[(size_t)k * HF + c];
      b = W[(size_t)(k + 1) * HF + c];
    }
    Wt[c * 20 + kp] = pack_bf16(a, b);
  }
}

__device__ __forceinline__ void scores_epilogue(
    const f32x4v* acc, const float* __restrict__ attn_l,
    const float* __restrict__ attn_r, float* __restrict__ el,
    float* __restrict__ er, int n0, int w, int q, int cc, int N) {
#pragma unroll
  for (int r = 0; r < 4; ++r) {
    int n = n0 + w * 16 + q * 4 + r;
    float pls[4], prs[4];
#pragma unroll
    for (int h = 0; h < 4; ++h) {
      float pl = acc[2 * h][r] * attn_l[h * 32 + cc] +
                 acc[2 * h + 1][r] * attn_l[h * 32 + 16 + cc];
      float pr = acc[2 * h][r] * attn_r[h * 32 + cc] +
                 acc[2 * h + 1][r] * attn_r[h * 32 + 16 + cc];
#pragma unroll
      for (int off = 1; off < 16; off <<= 1) {
        pl += __shfl_xor(pl, off);
        pr += __shfl_xor(pr, off);
      }
      pls[h] = pl;
      prs[h] = pr;
    }
    if (cc == 0 && n < N) {
#pragma unroll
      for (int h = 0; h < 4; ++h) {
        el[n * HEADS + h] = pls[h];
        er[n * HEADS + h] = prs[h];
      }
    }
  }
}

// Single-matrix MFMA GEMM + scores (layer 2). out bf16.
template <int K, typename XT>
__global__ __launch_bounds__(256) void mfma_gemm(
    const XT* __restrict__ X, const float* __restrict__ W,
    const float* __restrict__ attn_l, const float* __restrict__ attn_r,
    bf16* __restrict__ out, float* __restrict__ el, float* __restrict__ er,
    int N) {
  __shared__ __align__(16) unsigned Xl[64 * 20];
  __shared__ __align__(16) unsigned Wt[128 * 20];
  const int tid = threadIdx.x;
  const int w = tid >> 6;
  const int lane = tid & 63;
  const int cc = lane & 15;
  const int q = lane >> 4;
  const int n0 = blockIdx.x * 64;

  f32x4v acc[8];
#pragma unroll
  for (int t = 0; t < 8; ++t) acc[t] = f32x4v{0.f, 0.f, 0.f, 0.f};

  constexpr int KSTEPS = (K + 31) / 32;
  for (int ks = 0; ks < KSTEPS; ++ks) {
    int k0 = ks * 32;
    stage_X<XT, K>(X, Xl, n0, k0, N, tid);
    stage_W<K>(W, Wt, k0, tid);
    __syncthreads();
    bf16x8v a = *(const bf16x8v*)&Xl[(w * 16 + cc) * 20 + q * 4];
#pragma unroll
    for (int t = 0; t < 8; ++t) {
      bf16x8v b = *(const bf16x8v*)&Wt[(t * 16 + cc) * 20 + q * 4];
      acc[t] = __builtin_amdgcn_mfma_f32_16x16x32_bf16(a, b, acc[t], 0, 0, 0);
    }
    __syncthreads();
  }
#pragma unroll
  for (int r = 0; r < 4; ++r) {
    int n = n0 + w * 16 + q * 4 + r;
    if (n < N) {
#pragma unroll
      for (int t = 0; t < 8; ++t)
        out[(size_t)n * HF + t * 16 + cc] = __float2bfloat16(acc[t][r]);
    }
  }
  scores_epilogue(acc, attn_l, attn_r, el, er, n0, w, q, cc, N);
}

// Dual-matrix MFMA GEMM (layer 1): W1=fc1 -> outA + scores, W2=res1 -> outB.
template <int K>
__global__ __launch_bounds__(256) void mfma_dual(
    const float* __restrict__ X, const float* __restrict__ W1,
    const float* __restrict__ W2, const float* __restrict__ attn_l,
    const float* __restrict__ attn_r, bf16* __restrict__ outA,
    bf16* __restrict__ outB, float* __restrict__ el, float* __restrict__ er,
    int N) {
  __shared__ __align__(16) unsigned Xl[64 * 20];
  __shared__ __align__(16) unsigned Wt1[128 * 20];
  __shared__ __align__(16) unsigned Wt2[128 * 20];
  const int tid = threadIdx.x;
  const int w = tid >> 6;
  const int lane = tid & 63;
  const int cc = lane & 15;
  const int q = lane >> 4;
  const int n0 = blockIdx.x * 64;

  f32x4v acc1[8], acc2[8];
#pragma unroll
  for (int t = 0; t < 8; ++t) {
    acc1[t] = f32x4v{0.f, 0.f, 0.f, 0.f};
    acc2[t] = f32x4v{0.f, 0.f, 0.f, 0.f};
  }

  constexpr int KSTEPS = (K + 31) / 32;
  for (int ks = 0; ks < KSTEPS; ++ks) {
    int k0 = ks * 32;
    stage_X<float, K>(X, Xl, n0, k0, N, tid);
    stage_W<K>(W1, Wt1, k0, tid);
    stage_W<K>(W2, Wt2, k0, tid);
    __syncthreads();
    bf16x8v a = *(const bf16x8v*)&Xl[(w * 16 + cc) * 20 + q * 4];
#pragma unroll
    for (int t = 0; t < 8; ++t) {
      bf16x8v b1 = *(const bf16x8v*)&Wt1[(t * 16 + cc) * 20 + q * 4];
      bf16x8v b2 = *(const bf16x8v*)&Wt2[(t * 16 + cc) * 20 + q * 4];
      acc1[t] = __builtin_amdgcn_mfma_f32_16x16x32_bf16(a, b1, acc1[t], 0, 0, 0);
      acc2[t] = __builtin_amdgcn_mfma_f32_16x16x32_bf16(a, b2, acc2[t], 0, 0, 0);
    }
    __syncthreads();
  }
#pragma unroll
  for (int r = 0; r < 4; ++r) {
    int n = n0 + w * 16 + q * 4 + r;
    if (n < N) {
#pragma unroll
      for (int t = 0; t < 8; ++t) {
        outA[(size_t)n * HF + t * 16 + cc] = __float2bfloat16(acc1[t][r]);
        outB[(size_t)n * HF + t * 16 + cc] = __float2bfloat16(acc2[t][r]);
      }
    }
  }
  scores_epilogue(acc1, attn_l, attn_r, el, er, n0, w, q, cc, N);
}

// ============================ CSR build ====================================
// hist + readout-buffer init (folded: saves a launch).
__global__ __launch_bounds__(256) void hist_kernel(
    const int* __restrict__ dst, int* __restrict__ deg,
    float* __restrict__ hsum, unsigned* __restrict__ hmax, int E, int g32) {
  int e = blockIdx.x * 256 + threadIdx.x;
  if (e < g32) {
    hsum[e] = 0.f;
    hmax[e] = NEG_INF_ENC;
  }
  if (e < E) atomicAdd(&deg[dst[e]], 1);
}

__global__ __launch_bounds__(256) void scan1_kernel(
    const int* __restrict__ deg, int* __restrict__ row_ptr,
    int* __restrict__ bsum, int N) {
  const int base = blockIdx.x * 2048;
  const int tbase = base + threadIdx.x * 8;
  int vals[8];
  int tsum = 0;
#pragma unroll
  for (int i = 0; i < 8; ++i) {
    int idx = tbase + i;
    vals[i] = (idx < N) ? deg[idx] : 0;
    tsum += vals[i];
  }
  const int lane = threadIdx.x & 63, wv = threadIdx.x >> 6;
  int incl = tsum;
#pragma unroll
  for (int off = 1; off < 64; off <<= 1) {
    int nv = __shfl_up(incl, off);
    if (lane >= off) incl += nv;
  }
  __shared__ int wsum[4];
  if (lane == 63) wsum[wv] = incl;
  __syncthreads();
  int woff = 0;
  for (int w = 0; w < wv; ++w) woff += wsum[w];
  int run = woff + incl - tsum;
#pragma unroll
  for (int i = 0; i < 8; ++i) {
    int idx = tbase + i;
    if (idx < N) row_ptr[idx] = run;
    run += vals[i];
  }
  if (threadIdx.x == 255) bsum[blockIdx.x] = woff + incl;
}

__global__ __launch_bounds__(64) void scan2_kernel(
    const int* __restrict__ bsum, int* __restrict__ bpre, int NB) {
  const int lane = threadIdx.x;
  int running = 0;
  for (int c = 0; c < NB; c += 64) {
    int v = (c + lane < NB) ? bsum[c + lane] : 0;
    int incl = v;
#pragma unroll
    for (int off = 1; off < 64; off <<= 1) {
      int nv = __shfl_up(incl, off);
      if (lane >= off) incl += nv;
    }
    if (c + lane < NB) bpre[c + lane] = running + incl - v;
    running += __shfl(incl, 63);
  }
}

__global__ __launch_bounds__(256) void scan3_kernel(
    int* __restrict__ row_ptr, const int* __restrict__ bpre, int N, int E) {
  int t = blockIdx.x * 256 + threadIdx.x;
  if (t < N) row_ptr[t] += bpre[t >> 11];
  if (t == 0) row_ptr[N] = E;
}

__global__ __launch_bounds__(256) void scatter_kernel(
    const int* __restrict__ src, const int* __restrict__ dst,
    const int* __restrict__ row_ptr, int* __restrict__ cursor,
    int* __restrict__ ssorted, int E) {
  int e = blockIdx.x * 256 + threadIdx.x;
  if (e >= E) return;
  int d = dst[e];
  int pos = row_ptr[d] + atomicAdd(&cursor[d], 1);
  ssorted[pos] = src[e];
}

// ============ fused softmax + aggregate (single edge pass) =================
// One wave per node; lane holds cols (2*lane, 2*lane+1), head h = lane>>4.
// 8-edge bursts: edge indices fetched with ONE 32B vector load + __shfl
// broadcasts; tail is a single predicated 8-burst with clamped indices.
// alpha = exp(v)/sum(exp), no max-subtraction (v bounded).

#define E8_LOAD(i)                                                          \
  int s##i = __shfl(sv, i);                                                 \
  float xl##i = el[s##i * HEADS + h];                                       \
  unsigned fu##i = *(const unsigned*)&feat[(size_t)s##i * HF + c2];
#define E8_CALC(i)                                                          \
  {                                                                         \
    float xx = __expf(lrelu(xl##i + ern));                                  \
    float2 ff = unpack_bf16(fu##i);                                         \
    ssum += xx;                                                             \
    ax = fmaf(xx, ff.x, ax);                                                \
    ay = fmaf(xx, ff.y, ay);                                                \
  }
#define E8_CALC_PRED(i, e_)                                                 \
  {                                                                         \
    float xx = __expf(lrelu(xl##i + ern));                                  \
    xx = ((e_) + i < re) ? xx : 0.f;                                        \
    float2 ff = unpack_bf16(fu##i);                                         \
    ssum += xx;                                                             \
    ax = fmaf(xx, ff.x, ax);                                                \
    ay = fmaf(xx, ff.y, ay);                                                \
  }

#define AGG_LOOP                                                            \
  float ax = 0.f, ay = 0.f, ssum = 0.f;                                     \
  int e = rb;                                                               \
  for (; e + 8 <= re; e += 8) {                                             \
    int sv = ssorted[e + (lane & 7)];                                       \
    E8_LOAD(0) E8_LOAD(1) E8_LOAD(2) E8_LOAD(3)                             \
    E8_LOAD(4) E8_LOAD(5) E8_LOAD(6) E8_LOAD(7)                             \
    E8_CALC(0) E8_CALC(1) E8_CALC(2) E8_CALC(3)                             \
    E8_CALC(4) E8_CALC(5) E8_CALC(6) E8_CALC(7)                             \
  }                                                                         \
  if (e < re) {                                                             \
    int sv = ssorted[min(e + (lane & 7), re - 1)];                          \
    E8_LOAD(0) E8_LOAD(1) E8_LOAD(2) E8_LOAD(3)                             \
    E8_LOAD(4) E8_LOAD(5) E8_LOAD(6) E8_LOAD(7)                             \
    E8_CALC_PRED(0, e) E8_CALC_PRED(1, e) E8_CALC_PRED(2, e)                \
    E8_CALC_PRED(3, e) E8_CALC_PRED(4, e) E8_CALC_PRED(5, e)                \
    E8_CALC_PRED(6, e) E8_CALC_PRED(7, e)                                   \
  }

// Layer 1 epilogue: H[n] = elu(inv*agg + res[n] + bias)   (res, H bf16)
__global__ __launch_bounds__(256) void agg1_fused(
    const int* __restrict__ row_ptr, const int* __restrict__ ssorted,
    const float* __restrict__ el, const float* __restrict__ er,
    const bf16* __restrict__ feat, const bf16* __restrict__ res,
    bf16* __restrict__ H, const float* __restrict__ bias, int N) {
  int n = blockIdx.x * 4 + (threadIdx.x >> 6);
  if (n >= N) return;
  const int lane = threadIdx.x & 63;
  const int c2 = lane * 2, h = lane >> 4;
  const int rb = row_ptr[n], re = row_ptr[n + 1];
  const float ern = er[n * HEADS + h];

  AGG_LOOP

  float inv = 1.f / ssum;
  float2 r = unpack_bf16(*(const unsigned*)&res[(size_t)n * HF + c2]);
  float2 bi = *(const float2*)&bias[c2];
  float vx = fmaf(ax, inv, r.x + bi.x);
  float vy = fmaf(ay, inv, r.y + bi.y);
  vx = (vx > 0.f) ? vx : expm1f(vx);
  vy = (vy > 0.f) ? vy : expm1f(vy);
  *(unsigned*)&H[(size_t)n * HF + c2] = pack_bf16(vx, vy);
}

// Layer 2 epilogue: head-mean -> sigmoid gate -> readout atomics.
__global__ __launch_bounds__(256) void agg2_fused(
    const int* __restrict__ row_ptr, const int* __restrict__ ssorted,
    const float* __restrict__ el, const float* __restrict__ er,
    const bf16* __restrict__ feat, const bf16* __restrict__ h1,
    const float* __restrict__ bias, const float* __restrict__ ww,
    const float* __restrict__ wb, const int* __restrict__ gids,
    float* __restrict__ hsum, unsigned* __restrict__ hmax, int N) {
  int n = blockIdx.x * 4 + (threadIdx.x >> 6);
  if (n >= N) return;
  const int lane = threadIdx.x & 63;
  const int c2 = lane * 2, h = lane >> 4;
  const int rb = row_ptr[n], re = row_ptr[n + 1];
  const float ern = er[n * HEADS + h];

  AGG_LOOP

  float inv = 1.f / ssum;
  float2 r = unpack_bf16(*(const unsigned*)&h1[(size_t)n * HF + c2]);
  float2 bi = *(const float2*)&bias[c2];
  ax = fmaf(ax, inv, r.x + bi.x);
  ay = fmaf(ay, inv, r.y + bi.y);
  // head mean: after xor 16,32 every lane holds the sum over its 4-head class
#pragma unroll
  for (int off = 16; off < 64; off <<= 1) {
    ax += __shfl_xor(ax, off);
    ay += __shfl_xor(ay, off);
  }
  ax *= 0.25f;
  ay *= 0.25f;
  // sigmoid gate: dot(node_feats, ww) reduced over the 16-lane col groups
  int c = c2 & 31;
  float d = fmaf(ax, ww[c], ay * ww[c + 1]);
#pragma unroll
  for (int off = 1; off < 16; off <<= 1) d += __shfl_xor(d, off);
  float wv = 1.f / (1.f + __expf(-(d + wb[0])));
  if (lane < 16) {
    int g = gids[n];
    atomicAdd(&hsum[g * OUTF + c], wv * ax);
    atomicAdd(&hsum[g * OUTF + c + 1], wv * ay);
    atomicMax(&hmax[g * OUTF + c], enc_f(ax));
    atomicMax(&hmax[g * OUTF + c + 1], enc_f(ay));
  }
}

// ============================ readout tail =================================
__global__ __launch_bounds__(256) void final_gemm_kernel(
    const float* __restrict__ hsum, const unsigned* __restrict__ hmax,
    const float* __restrict__ tw, const float* __restrict__ tb,
    float* __restrict__ out, int G) {
  __shared__ float tws[64 * PRED_DIM];
  for (int i = threadIdx.x; i < 64 * PRED_DIM; i += 256) tws[i] = tw[i];
  __syncthreads();
  int g = blockIdx.x * 2 + (threadIdx.x >> 7);
  int p = threadIdx.x & 127;
  if (g >= G) return;
  float acc = tb[p];
#pragma unroll
  for (int k = 0; k < OUTF; ++k)
    acc = fmaf(hsum[g * OUTF + k], tws[k * PRED_DIM + p], acc);
#pragma unroll
  for (int k = 0; k < OUTF; ++k)
    acc = fmaf(dec_f(hmax[g * OUTF + k]), tws[(OUTF + k) * PRED_DIM + p], acc);
  out[(size_t)g * PRED_DIM + p] = acc;
}

static inline int cdiv(long long a, int b) { return (int)((a + b - 1) / b); }

extern "C" void kernel_launch(void* const* d_in, const int* in_sizes, int n_in,
                              void* d_out, int out_size, void* d_ws,
                              size_t ws_size, hipStream_t stream) {
  const float* feats   = (const float*)d_in[0];
  const int*   src     = (const int*)d_in[1];
  const int*   dst     = (const int*)d_in[2];
  const int*   gids    = (const int*)d_in[3];
  const float* fc1_w   = (const float*)d_in[4];
  const float* attn_l1 = (const float*)d_in[5];
  const float* attn_r1 = (const float*)d_in[6];
  const float* res1_w  = (const float*)d_in[7];
  const float* bias1   = (const float*)d_in[8];
  const float* fc2_w   = (const float*)d_in[9];
  const float* attn_l2 = (const float*)d_in[10];
  const float* attn_r2 = (const float*)d_in[11];
  const float* bias2   = (const float*)d_in[12];
  const float* ww      = (const float*)d_in[13];
  const float* wb      = (const float*)d_in[14];
  const float* tw      = (const float*)d_in[15];
  const float* tb      = (const float*)d_in[16];
  float* out = (float*)d_out;

  const int N = in_sizes[0] / IN_FEATS;  // 100000
  const int E = in_sizes[1];             // 900000
  const int G = out_size / PRED_DIM;     // 2048
  const int NB = cdiv(N, 2048);

  // ---- workspace layout ----
  bf16* A = (bf16*)d_ws;                      // N*128 bf16 (feat1/feat2)
  bf16* B = A + (size_t)N * HF;               // N*128 bf16 (res1)
  bf16* H = B + (size_t)N * HF;               // N*128 bf16 (h1)
  float* el = (float*)(H + (size_t)N * HF);   // N*4
  float* er = el + (size_t)N * HEADS;         // N*4
  float* hsum = er + (size_t)N * HEADS;       // G*32
  unsigned* hmax = (unsigned*)(hsum + (size_t)G * OUTF);  // G*32
  int* deg     = (int*)(hmax + (size_t)G * OUTF);  // N
  int* cursor  = deg + N;                          // N (contiguous w/ deg)
  int* row_ptr = cursor + N;                       // N+1
  int* ssorted = row_ptr + (N + 1);                // E
  int* bsum    = ssorted + E;                      // NB
  int* bpre    = bsum + NB;                        // NB

  const int gblk = cdiv(N, 64);
  const int nwblk = cdiv(N, 4);

  // ===================== CSR build =====================
  hipMemsetAsync(deg, 0, (size_t)2 * N * sizeof(int), stream);  // deg+cursor
  hist_kernel<<<cdiv(E, 256), 256, 0, stream>>>(dst, deg, hsum, hmax, E,
                                                G * OUTF);
  scan1_kernel<<<NB, 256, 0, stream>>>(deg, row_ptr, bsum, N);
  scan2_kernel<<<1, 64, 0, stream>>>(bsum, bpre, NB);
  scan3_kernel<<<cdiv(N, 256), 256, 0, stream>>>(row_ptr, bpre, N, E);
  scatter_kernel<<<cdiv(E, 256), 256, 0, stream>>>(src, dst, row_ptr, cursor,
                                                   ssorted, E);

  // ===================== Layer 1 =====================
  mfma_dual<IN_FEATS><<<gblk, 256, 0, stream>>>(
      feats, fc1_w, res1_w, attn_l1, attn_r1, A, B, el, er, N);
  agg1_fused<<<nwblk, 256, 0, stream>>>(row_ptr, ssorted, el, er, A, B, H,
                                        bias1, N);

  // ===================== Layer 2 =====================
  mfma_gemm<HF, bf16><<<gblk, 256, 0, stream>>>(
      H, fc2_w, attn_l2, attn_r2, A, el, er, N);
  agg2_fused<<<nwblk, 256, 0, stream>>>(row_ptr, ssorted, el, er, A, H, bias2,
                                        ww, wb, gids, hsum, hmax, N);

  // ===================== Readout =====================
  final_gemm_kernel<<<cdiv(G, 2), 256, 0, stream>>>(hsum, hmax, tw, tb, out, G);
}